// Round 5
// baseline (1496.128 us; speedup 1.0000x reference)
//
#include <hip/hip_runtime.h>
#include <cstdint>
#include <cstddef>

// ---------------------------------------------------------------------------
// DualAttention: B=1024, L=196, H=1024, A=512
// R5: k_channel rewritten with k_spatial's pipelined skeleton:
//   - panels (WctP) = MFMA A-operand (rows=a, k=l, zero-padded l>=196)
//   - att-tile = MFMA B-operand (cols=h, k=l), 64h x 32l bf16 per step,
//     double-buffered, staged via depth-2 reg pipeline of coalesced reads
//   - panels double-buffered via global_load_lds; ONE barrier per k-step
//   - epilogue params (p_h+b_ch, w_beta) staged in LDS, broadcast reads
// k_spatial / softmax / weighted unchanged from R4.
// ---------------------------------------------------------------------------

#define DEVI __device__ __forceinline__

typedef __bf16 bf16;
typedef bf16 bf16x4 __attribute__((ext_vector_type(4)));
typedef bf16 bf16x8 __attribute__((ext_vector_type(8)));
typedef float f32x4 __attribute__((ext_vector_type(4)));
typedef unsigned int uint32;

static constexpr int Bb = 1024;
static constexpr int Ll = 196;
static constexpr int Hh = 1024;
static constexpr int BL = Bb * Ll;        // 200704

DEVI void async16(const void* g, void* l) {
  __builtin_amdgcn_global_load_lds(
      (const __attribute__((address_space(1))) void*)g,
      (__attribute__((address_space(3))) void*)l, 16, 0, 0);
}

DEVI float fast_tanh(float x) {
  float e = __expf(2.f * x);
  return 1.f - 2.f * __builtin_amdgcn_rcpf(e + 1.f);
}

DEVI uint32 packbf2(float a, float b) {
  union { bf16 h; unsigned short u; } x, y;
  x.h = (bf16)a; y.h = (bf16)b;
  return (uint32)x.u | ((uint32)y.u << 16);
}

// --------------------- weight panel builders (run once) --------------------
// Panels: [k0/32][a=0..511][64B]; 16B slot s holds k-octet (s ^ g(a)),
// g(a) = (a>>1)&3  (XOR baked at build; GEMM reads slot l4^g).
__global__ void k_build_wt(const float* __restrict__ W, bf16* __restrict__ P) {
  int idx = blockIdx.x * 256 + threadIdx.x;      // 65536
  int a = idx & 511;
  int ko = (idx >> 9) << 3;
  bf16x8 v;
#pragma unroll
  for (int j = 0; j < 8; ++j) v[j] = (bf16)W[(size_t)(ko + j) * 512 + a];
  int panel = ko >> 5;
  int slot = ((ko >> 3) & 3) ^ ((a >> 1) & 3);
  *reinterpret_cast<bf16x8*>((char*)P + (size_t)panel * 32768 + a * 64 + slot * 16) = v;
}

__global__ void k_build_wct(const float* __restrict__ W, bf16* __restrict__ P) {
  int idx = blockIdx.x * 256 + threadIdx.x;      // 14336
  int a = idx & 511;
  int lo = (idx >> 9) << 3;
  bf16x8 v;
#pragma unroll
  for (int j = 0; j < 8; ++j)
    v[j] = (lo + j < Ll) ? (bf16)W[(size_t)(lo + j) * 512 + a] : (bf16)0.f;
  int panel = lo >> 5;
  int slot = ((lo >> 3) & 3) ^ ((a >> 1) & 3);
  *reinterpret_cast<bf16x8*>((char*)P + (size_t)panel * 32768 + a * 64 + slot * 16) = v;
}

// ------------------------------- p_h = h@W_h -------------------------------
__global__ void k_ph(const float* __restrict__ h, const float* __restrict__ W_h,
                     const float* __restrict__ b_h, float* __restrict__ p_h) {
  int a = blockIdx.x * 256 + threadIdx.x;
  int b0 = blockIdx.y * 8;
  float acc[8] = {0.f, 0.f, 0.f, 0.f, 0.f, 0.f, 0.f, 0.f};
  for (int k = 0; k < 1024; ++k) {
    float w = W_h[(size_t)k * 512 + a];
#pragma unroll
    for (int i = 0; i < 8; ++i) acc[i] += h[(size_t)(b0 + i) * 1024 + k] * w;
  }
#pragma unroll
  for (int i = 0; i < 8; ++i) p_h[(size_t)(b0 + i) * 512 + a] = acc[i] + b_h[a];
}

// ---------------- spatial branch: fused GEMM + tanh-dot reduce -------------
// grid = BL/64 = 3136, 256 thr; tile 64 x 512, K=1024, 32 steps.
// LDS: B dbuf 2x32KB at 0, A dbuf 2x5120B at 65536.  One barrier per step.
#define SPB(p) ((p) * 32768)
#define SPA(p) (65536 + (p) * 5120)
#define SP_ASTR 80
__launch_bounds__(256)
__global__ void k_spatial(const float* __restrict__ att, const bf16* __restrict__ WtP,
                          const float* __restrict__ b_att, const float* __restrict__ p_h,
                          const float* __restrict__ w_alpha, float* __restrict__ logits_s) {
  __shared__ alignas(1024) char lds[65536 + 2 * 5120];
  const int tid = threadIdx.x;
  const int lane = tid & 63;
  const int wn = tid >> 6;
  const int l15 = lane & 15, l4 = lane >> 4;
  const size_t row0 = (size_t)blockIdx.x * 64;
  const int slotB = ((l4 ^ ((l15 >> 1) & 3)) << 4);
  const int ar = tid >> 2;                  // A rows 0..63
  const int aks = (tid & 3) << 3;           // k offset 0,8,16,24
  const char* WtPc = (const char*)WtP;
  const float* apbase = att + (row0 + ar) * 1024 + aks;
  const int awoff = ar * SP_ASTR + (aks << 1);

  f32x4 acc[4][8];
#pragma unroll
  for (int m = 0; m < 4; ++m)
#pragma unroll
    for (int n = 0; n < 8; ++n) acc[m][n] = f32x4{0.f, 0.f, 0.f, 0.f};

  // prologue: A0 -> regs -> Abuf0; B0 glls -> Bbuf0; A1 -> regs
  float4 c0 = *reinterpret_cast<const float4*>(apbase);
  float4 c1 = *reinterpret_cast<const float4*>(apbase + 4);
#pragma unroll
  for (int j = 0; j < 8; ++j) {
    int c = (j << 2) + wn;
    async16(WtPc + c * 1024 + lane * 16, &lds[SPB(0) + c * 1024]);
  }
  {
    bf16x4 w0 = {(bf16)c0.x, (bf16)c0.y, (bf16)c0.z, (bf16)c0.w};
    bf16x4 w1 = {(bf16)c1.x, (bf16)c1.y, (bf16)c1.z, (bf16)c1.w};
    *reinterpret_cast<bf16x4*>(&lds[SPA(0) + awoff]) = w0;
    *reinterpret_cast<bf16x4*>(&lds[SPA(0) + awoff + 8]) = w1;
  }
  c0 = *reinterpret_cast<const float4*>(apbase + 32);
  c1 = *reinterpret_cast<const float4*>(apbase + 36);
  __syncthreads();

  for (int t = 0; t < 32; ++t) {
    const int p = t & 1;
    if (t < 31) {
      bf16x4 w0 = {(bf16)c0.x, (bf16)c0.y, (bf16)c0.z, (bf16)c0.w};
      bf16x4 w1 = {(bf16)c1.x, (bf16)c1.y, (bf16)c1.z, (bf16)c1.w};
      *reinterpret_cast<bf16x4*>(&lds[SPA(p ^ 1) + awoff]) = w0;
      *reinterpret_cast<bf16x4*>(&lds[SPA(p ^ 1) + awoff + 8]) = w1;
      const char* bsrc = WtPc + (size_t)(t + 1) * 32768;
#pragma unroll
      for (int j = 0; j < 8; ++j) {
        int c = (j << 2) + wn;
        async16(bsrc + c * 1024 + lane * 16, &lds[SPB(p ^ 1) + c * 1024]);
      }
      if (t < 30) {
        c0 = *reinterpret_cast<const float4*>(apbase + (t + 2) * 32);
        c1 = *reinterpret_cast<const float4*>(apbase + (t + 2) * 32 + 4);
      }
    }
    bf16x8 af[4];
#pragma unroll
    for (int m = 0; m < 4; ++m)
      af[m] = *reinterpret_cast<const bf16x8*>(
          &lds[SPA(p) + (m * 16 + l15) * SP_ASTR + (l4 << 4)]);
#pragma unroll
    for (int n = 0; n < 8; ++n) {
      bf16x8 bv = *reinterpret_cast<const bf16x8*>(
          &lds[SPB(p) + (wn * 128 + n * 16 + l15) * 64 + slotB]);
#pragma unroll
      for (int m = 0; m < 4; ++m)
        acc[m][n] = __builtin_amdgcn_mfma_f32_16x16x32_bf16(af[m], bv, acc[m][n], 0, 0, 0);
    }
    __syncthreads();
  }

  // epilogue
  float wa[8], ba[8], ph0[8], ph1[8];
  unsigned b0i = (unsigned)row0 / 196u;
  unsigned b1i = (unsigned)(row0 + 63) / 196u;
  unsigned bnd = (b0i + 1) * 196u;
#pragma unroll
  for (int n = 0; n < 8; ++n) {
    int a = wn * 128 + n * 16 + l15;
    wa[n] = w_alpha[a];
    ba[n] = b_att[a];
    ph0[n] = p_h[(size_t)b0i * 512 + a];
    ph1[n] = p_h[(size_t)b1i * 512 + a];
  }
  float* red = reinterpret_cast<float*>(lds);
#pragma unroll
  for (int m = 0; m < 4; ++m) {
#pragma unroll
    for (int j = 0; j < 4; ++j) {
      int rloc = m * 16 + l4 * 4 + j;
      unsigned R = (unsigned)row0 + rloc;
      bool hib = R >= bnd;
      float s = 0.f;
#pragma unroll
      for (int n = 0; n < 8; ++n)
        s += fast_tanh(acc[m][n][j] + ba[n] + (hib ? ph1[n] : ph0[n])) * wa[n];
      s += __shfl_xor(s, 1);
      s += __shfl_xor(s, 2);
      s += __shfl_xor(s, 4);
      s += __shfl_xor(s, 8);
      if (l15 == 0) red[wn * 64 + rloc] = s;
    }
  }
  __syncthreads();
  if (tid < 64)
    logits_s[row0 + tid] = red[tid] + red[64 + tid] + red[128 + tid] + red[192 + tid];
}

// ---------------- channel branch: fused GEMM + tanh-dot reduce -------------
// grid = (16 h-tiles, 1024 b), 256 thr.  D[a,h] = sum_l Wct[a,l]*att[b,l,h].
// Panels = MFMA A-operand (dbuf glls); att-tile 64h x 32l bf16 = B-operand
// (dbuf, depth-2 reg pipeline, XOR-swizzled l-slots). One barrier per step.
#define CHB(p) ((p) * 32768)
#define CHA(p) (65536 + (p) * 5120)
#define CH_TSTR 80
#define CH_PHC 75776
#define CH_WB  77824
__launch_bounds__(256)
__global__ void k_channel(const float* __restrict__ att, const bf16* __restrict__ WctP,
                          const float* __restrict__ b_ch, const float* __restrict__ p_h,
                          const float* __restrict__ w_beta, float* __restrict__ logits_c) {
  __shared__ alignas(1024) char lds[79872];
  const int tid = threadIdx.x;
  const int lane = tid & 63;
  const int wn = tid >> 6;
  const int l15 = lane & 15, l4 = lane >> 4;
  const int b = blockIdx.y;
  const int h0 = blockIdx.x * 64;
  const float* attb = att + (size_t)b * Ll * 1024;
  const char* Pc = (const char*)WctP;
  // panel (A-op) frag: row a, k-octet l4, baked XOR slot
  const int slotP = (l4 ^ ((l15 >> 1) & 3)) << 4;
  // att-tile (B-op) frag: row h, l-octet l4, staging XOR slot
  const int slotT = (l4 ^ ((l15 >> 2) & 3)) << 4;
  // staging map: thread -> l-pair lp, h-quad hq
  const int lp = tid >> 4;                 // 0..15  (l = 2*lp, 2*lp+1)
  const int hq = (tid & 15) << 2;          // 0,4,...,60

  f32x4 acc[8][4];                         // [m: a-dim][n: h-dim]
#pragma unroll
  for (int m = 0; m < 8; ++m)
#pragma unroll
    for (int n = 0; n < 4; ++n) acc[m][n] = f32x4{0.f, 0.f, 0.f, 0.f};

  // epilogue params into LDS: phc = p_h + b_ch, wb = w_beta
  {
    float* phcL = reinterpret_cast<float*>(&lds[CH_PHC]);
    float* wbL = reinterpret_cast<float*>(&lds[CH_WB]);
    phcL[tid] = p_h[(size_t)b * 512 + tid] + b_ch[tid];
    phcL[tid + 256] = p_h[(size_t)b * 512 + tid + 256] + b_ch[tid + 256];
    wbL[tid] = w_beta[tid];
    wbL[tid + 256] = w_beta[tid + 256];
  }

  // --- att-tile staging helpers (depth-2 reg pipeline) ---
  float4 va, vb2;
  auto load_step = [&](int t) {
    int lg = t * 32 + 2 * lp;
    va = float4{0.f, 0.f, 0.f, 0.f};
    vb2 = float4{0.f, 0.f, 0.f, 0.f};
    if (lg < Ll)
      va = *reinterpret_cast<const float4*>(&attb[(size_t)lg * 1024 + h0 + hq]);
    if (lg + 1 < Ll)
      vb2 = *reinterpret_cast<const float4*>(&attb[(size_t)(lg + 1) * 1024 + h0 + hq]);
  };
  auto write_tile = [&](int p) {
    uint32 pk[4] = {packbf2(va.x, vb2.x), packbf2(va.y, vb2.y),
                    packbf2(va.z, vb2.z), packbf2(va.w, vb2.w)};
#pragma unroll
    for (int c = 0; c < 4; ++c) {
      int h = hq + c;
      int u = lp ^ (((h >> 2) & 3) << 2);
      *reinterpret_cast<uint32*>(&lds[CHA(p) + h * CH_TSTR + 4 * u]) = pk[c];
    }
  };

  // prologue: tile0 -> regs -> Abuf0; panel0 glls; tile1 -> regs
  load_step(0);
#pragma unroll
  for (int j = 0; j < 8; ++j) {
    int c = (j << 2) + wn;
    async16(Pc + c * 1024 + lane * 16, &lds[CHB(0) + c * 1024]);
  }
  write_tile(0);
  load_step(1);
  __syncthreads();

  for (int t = 0; t < 7; ++t) {
    const int p = t & 1;
    if (t < 6) {
      write_tile(p ^ 1);
      const char* bsrc = Pc + (size_t)(t + 1) * 32768;
#pragma unroll
      for (int j = 0; j < 8; ++j) {
        int c = (j << 2) + wn;
        async16(bsrc + c * 1024 + lane * 16, &lds[CHB(p ^ 1) + c * 1024]);
      }
      if (t < 5) load_step(t + 2);
    }
    bf16x8 av[8];
#pragma unroll
    for (int m = 0; m < 8; ++m) {
      int a = wn * 128 + m * 16 + l15;
      av[m] = *reinterpret_cast<const bf16x8*>(&lds[CHB(p) + a * 64 + slotP]);
    }
#pragma unroll
    for (int n = 0; n < 4; ++n) {
      int hh = n * 16 + l15;
      bf16x8 bv = *reinterpret_cast<const bf16x8*>(&lds[CHA(p) + hh * CH_TSTR + slotT]);
#pragma unroll
      for (int m = 0; m < 8; ++m)
        acc[m][n] = __builtin_amdgcn_mfma_f32_16x16x32_bf16(av[m], bv, acc[m][n], 0, 0, 0);
    }
    __syncthreads();
  }

  // epilogue: logits_c[b,h] = sum_a tanh(D[a,h] + phc[a]) * wb[a]
  const float* phcL = reinterpret_cast<const float*>(&lds[CH_PHC]);
  const float* wbL = reinterpret_cast<const float*>(&lds[CH_WB]);
  float sn[4] = {0.f, 0.f, 0.f, 0.f};
#pragma unroll
  for (int m = 0; m < 8; ++m) {
    int abase = wn * 128 + m * 16 + l4 * 4;
    float2 p01 = *reinterpret_cast<const float2*>(&phcL[abase]);
    float2 p23 = *reinterpret_cast<const float2*>(&phcL[abase + 2]);
    float2 w01 = *reinterpret_cast<const float2*>(&wbL[abase]);
    float2 w23 = *reinterpret_cast<const float2*>(&wbL[abase + 2]);
#pragma unroll
    for (int n = 0; n < 4; ++n) {
      sn[n] += fast_tanh(acc[m][n][0] + p01.x) * w01.x;
      sn[n] += fast_tanh(acc[m][n][1] + p01.y) * w01.y;
      sn[n] += fast_tanh(acc[m][n][2] + p23.x) * w23.x;
      sn[n] += fast_tanh(acc[m][n][3] + p23.y) * w23.y;
    }
  }
#pragma unroll
  for (int n = 0; n < 4; ++n) {
    sn[n] += __shfl_xor(sn[n], 16);
    sn[n] += __shfl_xor(sn[n], 32);
  }
  __syncthreads();
  float* red = reinterpret_cast<float*>(lds);   // panels done; reuse
  if (l4 == 0) {
#pragma unroll
    for (int n = 0; n < 4; ++n) red[wn * 64 + n * 16 + l15] = sn[n];
  }
  __syncthreads();
  if (tid < 64)
    logits_c[(size_t)b * 1024 + h0 + tid] =
        red[tid] + red[64 + tid] + red[128 + tid] + red[192 + tid];
}

// ------------------------------- softmaxes ---------------------------------
__global__ void k_softmax_s(const float* __restrict__ logits, float* __restrict__ wout) {
  int b = blockIdx.x, t = threadIdx.x;
  __shared__ float sm[8];
  float x = (t < Ll) ? logits[(size_t)b * Ll + t] : -1e30f;
  float m = x;
#pragma unroll
  for (int o = 32; o; o >>= 1) m = fmaxf(m, __shfl_xor(m, o));
  if ((t & 63) == 0) sm[t >> 6] = m;
  __syncthreads();
  m = fmaxf(fmaxf(sm[0], sm[1]), fmaxf(sm[2], sm[3]));
  float e = (t < Ll) ? __expf(x - m) : 0.f;
  float s = e;
#pragma unroll
  for (int o = 32; o; o >>= 1) s += __shfl_xor(s, o);
  if ((t & 63) == 0) sm[4 + (t >> 6)] = s;
  __syncthreads();
  s = sm[4] + sm[5] + sm[6] + sm[7];
  if (t < Ll) wout[(size_t)b * Ll + t] = e / s;
}

__global__ void k_softmax_c(const float* __restrict__ logits, float* __restrict__ wout) {
  int b = blockIdx.x, t = threadIdx.x;
  __shared__ float sm[8];
  float4 x = *reinterpret_cast<const float4*>(&logits[(size_t)b * 1024 + (t << 2)]);
  float m = fmaxf(fmaxf(x.x, x.y), fmaxf(x.z, x.w));
#pragma unroll
  for (int o = 32; o; o >>= 1) m = fmaxf(m, __shfl_xor(m, o));
  if ((t & 63) == 0) sm[t >> 6] = m;
  __syncthreads();
  m = fmaxf(fmaxf(sm[0], sm[1]), fmaxf(sm[2], sm[3]));
  float e0 = __expf(x.x - m), e1 = __expf(x.y - m);
  float e2 = __expf(x.z - m), e3 = __expf(x.w - m);
  float s = e0 + e1 + e2 + e3;
#pragma unroll
  for (int o = 32; o; o >>= 1) s += __shfl_xor(s, o);
  if ((t & 63) == 0) sm[4 + (t >> 6)] = s;
  __syncthreads();
  float r = 1.f / (sm[4] + sm[5] + sm[6] + sm[7]);
  float4 o4 = {e0 * r, e1 * r, e2 * r, e3 * r};
  *reinterpret_cast<float4*>(&wout[(size_t)b * 1024 + (t << 2)]) = o4;
}

// --------------- fused weighted sums: one pass over att --------------------
__launch_bounds__(256)
__global__ void k_weighted(const float* __restrict__ att, const float* __restrict__ wsp,
                           const float* __restrict__ wch, float* __restrict__ out_s,
                           float* __restrict__ out_c) {
  int b = blockIdx.x, t = threadIdx.x;
  int lane = t & 63, wave = t >> 6;
  __shared__ float wsl[Ll];
  __shared__ float chan[4][Ll];
  if (t < Ll) wsl[t] = wsp[(size_t)b * Ll + t];
  float4 wc = *reinterpret_cast<const float4*>(&wch[(size_t)b * 1024 + (t << 2)]);
  float4 accs = {0.f, 0.f, 0.f, 0.f};
  __syncthreads();
  const float* attb = att + (size_t)b * Ll * 1024;
  for (int l = 0; l < Ll; ++l) {
    float4 v = *reinterpret_cast<const float4*>(&attb[(size_t)l * 1024 + (t << 2)]);
    float w = wsl[l];
    accs.x += w * v.x; accs.y += w * v.y; accs.z += w * v.z; accs.w += w * v.w;
    float pc = wc.x * v.x + wc.y * v.y + wc.z * v.z + wc.w * v.w;
#pragma unroll
    for (int o = 32; o; o >>= 1) pc += __shfl_xor(pc, o);
    if (lane == 0) chan[wave][l] = pc;
  }
  *reinterpret_cast<float4*>(&out_s[(size_t)b * 1024 + (t << 2)]) = accs;
  __syncthreads();
  if (t < Ll)
    out_c[(size_t)b * Ll + t] = chan[0][t] + chan[1][t] + chan[2][t] + chan[3][t];
}

// ------------------------------- launcher ----------------------------------
extern "C" void kernel_launch(void* const* d_in, const int* in_sizes, int n_in,
                              void* d_out, int out_size, void* d_ws, size_t ws_size,
                              hipStream_t stream) {
  (void)in_sizes; (void)n_in; (void)out_size; (void)ws_size;
  const float* att     = (const float*)d_in[0];
  const float* h       = (const float*)d_in[1];
  const float* W_att   = (const float*)d_in[2];
  const float* b_att   = (const float*)d_in[3];
  const float* W_h     = (const float*)d_in[4];
  const float* b_h     = (const float*)d_in[5];
  const float* w_alpha = (const float*)d_in[6];
  const float* W_ch    = (const float*)d_in[8];
  const float* b_ch    = (const float*)d_in[9];
  const float* w_beta  = (const float*)d_in[10];
  // d_in[7] b_alpha, d_in[11] b_beta: softmax-shift-invariant, unused

  float* out_ws    = (float*)d_out;                       // [B,H]
  float* out_wc    = out_ws + (size_t)Bb * Hh;            // [B,L]
  float* out_wspat = out_wc + (size_t)Bb * Ll;            // [B,L]

  char* ws = (char*)d_ws;
  float* p_h      = (float*)(ws);                          // 2 MB
  float* logits_s = (float*)(ws + 2097152);                // 802816 B
  float* logits_c = (float*)(ws + 2899968);                // 4 MB
  float* w_chan   = (float*)(ws + 7094272);                // 4 MB
  bf16*  WtP      = (bf16*)(ws + 11288576);                // 1 MB (32 panels)
  bf16*  WctP     = (bf16*)(ws + 12337152);                // 224 KB (7 panels)

  k_build_wt<<<256, 256, 0, stream>>>(W_att, WtP);
  k_build_wct<<<56, 256, 0, stream>>>(W_ch, WctP);
  k_ph<<<dim3(2, 128), 256, 0, stream>>>(h, W_h, b_h, p_h);
  k_spatial<<<BL / 64, 256, 0, stream>>>(att, WtP, b_att, p_h, w_alpha, logits_s);
  k_channel<<<dim3(16, 1024), 256, 0, stream>>>(att, WctP, b_ch, p_h, w_beta, logits_c);
  k_softmax_s<<<1024, 256, 0, stream>>>(logits_s, out_wspat);
  k_softmax_c<<<1024, 256, 0, stream>>>(logits_c, w_chan);
  k_weighted<<<1024, 256, 0, stream>>>(att, out_wspat, w_chan, out_ws, out_wc);
}

// Round 6
// 1276.152 us; speedup vs baseline: 1.1724x; 1.1724x over previous
//
#include <hip/hip_runtime.h>
#include <cstdint>
#include <cstddef>

// ---------------------------------------------------------------------------
// DualAttention: B=1024, L=196, H=1024, A=512
// R6: occupancy-driven LDS budgets (reserve discovered in R5: >4KB/CU).
//  - k_channel (65 KB LDS -> 2 blocks/CU): att-tile staged ONCE for whole K
//    (64h x 224l bf16, stride 464, row-XOR quad swizzle); W-panels split into
//    a-halves (16 KB, dbuf, 14 steps x 1 barrier); acc[4][4]; per-half epilogue.
//  - k_spatial (42 KB LDS -> 3 blocks/CU): B panel single-buffered (issued
//    after consume-barrier, m97-style 2-barrier loop); A LDS-dbuf + depth-2
//    reg prefetch issued inside the MFMA window.
// ---------------------------------------------------------------------------

#define DEVI __device__ __forceinline__

typedef __bf16 bf16;
typedef bf16 bf16x4 __attribute__((ext_vector_type(4)));
typedef bf16 bf16x8 __attribute__((ext_vector_type(8)));
typedef float f32x4 __attribute__((ext_vector_type(4)));
typedef unsigned int uint32;

static constexpr int Bb = 1024;
static constexpr int Ll = 196;
static constexpr int Hh = 1024;
static constexpr int BL = Bb * Ll;        // 200704

DEVI void async16(const void* g, void* l) {
  __builtin_amdgcn_global_load_lds(
      (const __attribute__((address_space(1))) void*)g,
      (__attribute__((address_space(3))) void*)l, 16, 0, 0);
}

DEVI float fast_tanh(float x) {
  float e = __expf(2.f * x);
  return 1.f - 2.f * __builtin_amdgcn_rcpf(e + 1.f);
}

DEVI uint32 packbf2(float a, float b) {
  union { bf16 h; unsigned short u; } x, y;
  x.h = (bf16)a; y.h = (bf16)b;
  return (uint32)x.u | ((uint32)y.u << 16);
}

// --------------------- weight panel builders (run once) --------------------
// Panels: [k0/32][a=0..511][64B]; 16B slot s holds k-octet (s ^ g(a)),
// g(a) = (a>>1)&3  (XOR baked at build; GEMM reads slot l4^g).
__global__ void k_build_wt(const float* __restrict__ W, bf16* __restrict__ P) {
  int idx = blockIdx.x * 256 + threadIdx.x;      // 65536
  int a = idx & 511;
  int ko = (idx >> 9) << 3;
  bf16x8 v;
#pragma unroll
  for (int j = 0; j < 8; ++j) v[j] = (bf16)W[(size_t)(ko + j) * 512 + a];
  int panel = ko >> 5;
  int slot = ((ko >> 3) & 3) ^ ((a >> 1) & 3);
  *reinterpret_cast<bf16x8*>((char*)P + (size_t)panel * 32768 + a * 64 + slot * 16) = v;
}

__global__ void k_build_wct(const float* __restrict__ W, bf16* __restrict__ P) {
  int idx = blockIdx.x * 256 + threadIdx.x;      // 14336
  int a = idx & 511;
  int lo = (idx >> 9) << 3;
  bf16x8 v;
#pragma unroll
  for (int j = 0; j < 8; ++j)
    v[j] = (lo + j < Ll) ? (bf16)W[(size_t)(lo + j) * 512 + a] : (bf16)0.f;
  int panel = lo >> 5;
  int slot = ((lo >> 3) & 3) ^ ((a >> 1) & 3);
  *reinterpret_cast<bf16x8*>((char*)P + (size_t)panel * 32768 + a * 64 + slot * 16) = v;
}

// ------------------------------- p_h = h@W_h -------------------------------
__global__ void k_ph(const float* __restrict__ h, const float* __restrict__ W_h,
                     const float* __restrict__ b_h, float* __restrict__ p_h) {
  int a = blockIdx.x * 256 + threadIdx.x;
  int b0 = blockIdx.y * 8;
  float acc[8] = {0.f, 0.f, 0.f, 0.f, 0.f, 0.f, 0.f, 0.f};
  for (int k = 0; k < 1024; ++k) {
    float w = W_h[(size_t)k * 512 + a];
#pragma unroll
    for (int i = 0; i < 8; ++i) acc[i] += h[(size_t)(b0 + i) * 1024 + k] * w;
  }
#pragma unroll
  for (int i = 0; i < 8; ++i) p_h[(size_t)(b0 + i) * 512 + a] = acc[i] + b_h[a];
}

// ---------------- spatial branch: fused GEMM + tanh-dot reduce -------------
// grid = BL/64 = 3136, 256 thr; tile 64 x 512, K=1024, 32 steps.
// LDS 43008: B single 32KB at 0, A dbuf 2x5120 at 32768. 2 barriers/step.
#define SPA(p) (32768 + (p) * 5120)
#define SP_ASTR 80
__launch_bounds__(256)
__global__ void k_spatial(const float* __restrict__ att, const bf16* __restrict__ WtP,
                          const float* __restrict__ b_att, const float* __restrict__ p_h,
                          const float* __restrict__ w_alpha, float* __restrict__ logits_s) {
  __shared__ alignas(1024) char lds[43008];
  const int tid = threadIdx.x;
  const int lane = tid & 63;
  const int wn = tid >> 6;
  const int l15 = lane & 15, l4 = lane >> 4;
  const size_t row0 = (size_t)blockIdx.x * 64;
  const int slotB = ((l4 ^ ((l15 >> 1) & 3)) << 4);
  const int ar = tid >> 2;                  // A rows 0..63
  const int aks = (tid & 3) << 3;           // k offset 0,8,16,24
  const char* WtPc = (const char*)WtP;
  const float* apbase = att + (row0 + ar) * 1024 + aks;
  const int awoff = ar * SP_ASTR + (aks << 1);

  f32x4 acc[4][8];
#pragma unroll
  for (int m = 0; m < 4; ++m)
#pragma unroll
    for (int n = 0; n < 8; ++n) acc[m][n] = f32x4{0.f, 0.f, 0.f, 0.f};

  // prologue: A(0) -> regs -> Ab(0); issue B(0); issue A(1) -> regs
  float4 c0 = *reinterpret_cast<const float4*>(apbase);
  float4 c1 = *reinterpret_cast<const float4*>(apbase + 4);
  {
    bf16x4 w0 = {(bf16)c0.x, (bf16)c0.y, (bf16)c0.z, (bf16)c0.w};
    bf16x4 w1 = {(bf16)c1.x, (bf16)c1.y, (bf16)c1.z, (bf16)c1.w};
    *reinterpret_cast<bf16x4*>(&lds[SPA(0) + awoff]) = w0;
    *reinterpret_cast<bf16x4*>(&lds[SPA(0) + awoff + 8]) = w1;
  }
#pragma unroll
  for (int j = 0; j < 8; ++j) {
    int c = (j << 2) + wn;
    async16(WtPc + c * 1024 + lane * 16, &lds[c * 1024]);
  }
  c0 = *reinterpret_cast<const float4*>(apbase + 32);
  c1 = *reinterpret_cast<const float4*>(apbase + 36);

  for (int t = 0; t < 32; ++t) {
    const int p = t & 1;
    if (t < 31) {
      // write A(t+1) (regs issued >=1 step ago)
      bf16x4 w0 = {(bf16)c0.x, (bf16)c0.y, (bf16)c0.z, (bf16)c0.w};
      bf16x4 w1 = {(bf16)c1.x, (bf16)c1.y, (bf16)c1.z, (bf16)c1.w};
      *reinterpret_cast<bf16x4*>(&lds[SPA(p ^ 1) + awoff]) = w0;
      *reinterpret_cast<bf16x4*>(&lds[SPA(p ^ 1) + awoff + 8]) = w1;
    }
    __syncthreads();                        // B(t) + A(t+1)-writes ready
    if (t < 30) {                           // issue A(t+2): drains at barrier2,
      c0 = *reinterpret_cast<const float4*>(apbase + (t + 2) * 32);      // cover = MFMA
      c1 = *reinterpret_cast<const float4*>(apbase + (t + 2) * 32 + 4);
    }
    bf16x8 af[4];
#pragma unroll
    for (int m = 0; m < 4; ++m)
      af[m] = *reinterpret_cast<const bf16x8*>(
          &lds[SPA(p) + (m * 16 + l15) * SP_ASTR + (l4 << 4)]);
#pragma unroll
    for (int n = 0; n < 8; ++n) {
      bf16x8 bv = *reinterpret_cast<const bf16x8*>(
          &lds[(wn * 128 + n * 16 + l15) * 64 + slotB]);
#pragma unroll
      for (int m = 0; m < 4; ++m)
        acc[m][n] = __builtin_amdgcn_mfma_f32_16x16x32_bf16(af[m], bv, acc[m][n], 0, 0, 0);
    }
    __syncthreads();                        // B(t) consumed
    if (t < 31) {
      const char* bsrc = WtPc + (size_t)(t + 1) * 32768;
#pragma unroll
      for (int j = 0; j < 8; ++j) {
        int c = (j << 2) + wn;
        async16(bsrc + c * 1024 + lane * 16, &lds[c * 1024]);
      }
    }
  }

  // epilogue
  float wa[8], ba[8], ph0[8], ph1[8];
  unsigned b0i = (unsigned)row0 / 196u;
  unsigned b1i = (unsigned)(row0 + 63) / 196u;
  unsigned bnd = (b0i + 1) * 196u;
#pragma unroll
  for (int n = 0; n < 8; ++n) {
    int a = wn * 128 + n * 16 + l15;
    wa[n] = w_alpha[a];
    ba[n] = b_att[a];
    ph0[n] = p_h[(size_t)b0i * 512 + a];
    ph1[n] = p_h[(size_t)b1i * 512 + a];
  }
  float* red = reinterpret_cast<float*>(lds);
#pragma unroll
  for (int m = 0; m < 4; ++m) {
#pragma unroll
    for (int j = 0; j < 4; ++j) {
      int rloc = m * 16 + l4 * 4 + j;
      unsigned R = (unsigned)row0 + rloc;
      bool hib = R >= bnd;
      float s = 0.f;
#pragma unroll
      for (int n = 0; n < 8; ++n)
        s += fast_tanh(acc[m][n][j] + ba[n] + (hib ? ph1[n] : ph0[n])) * wa[n];
      s += __shfl_xor(s, 1);
      s += __shfl_xor(s, 2);
      s += __shfl_xor(s, 4);
      s += __shfl_xor(s, 8);
      if (l15 == 0) red[wn * 64 + rloc] = s;
    }
  }
  __syncthreads();
  if (tid < 64)
    logits_s[row0 + tid] = red[tid] + red[64 + tid] + red[128 + tid] + red[192 + tid];
}

// ---------------- channel branch: fused GEMM + tanh-dot reduce -------------
// grid = (16 h-tiles, 1024 b), 256 thr. D[a,h] = sum_l Wct[a,l]*att[b,l,h].
// att-tile staged ONCE for whole K (64h x 224l bf16, stride 464, row-XOR quad
// swizzle). Panels split into a-halves (16KB dbuf), 14 steps x 1 barrier.
#define CHB(p)  ((p) * 16384)
#define CH_TOFF 32768
#define CH_TSTR 464
#define CH_PHC  62464
#define CH_WB   64512
#define CH_LDSZ 66560
__launch_bounds__(256)
__global__ void k_channel(const float* __restrict__ att, const bf16* __restrict__ WctP,
                          const float* __restrict__ b_ch, const float* __restrict__ p_h,
                          const float* __restrict__ w_beta, float* __restrict__ logits_c) {
  __shared__ alignas(1024) char lds[CH_LDSZ];
  const int tid = threadIdx.x;
  const int lane = tid & 63;
  const int wn = tid >> 6;
  const int l15 = lane & 15, l4 = lane >> 4;
  const int b = blockIdx.y;
  const int h0 = blockIdx.x * 64;
  const float* attb = att + (size_t)b * Ll * 1024 + h0;
  const char* Pc = (const char*)WctP;
  const int slotP = (l4 ^ ((l15 >> 1) & 3)) << 4;     // panel read (baked XOR)
  const int slotT = (l4 ^ ((l15 >> 2) & 3)) << 4;     // tile read (row-XOR)
  const int lp = tid >> 4;                            // l-pair 0..15
  const int hq = (tid & 15) << 2;                     // h 0,4,...,60
  const int usw = lp ^ (((tid & 15) & 3) << 2);       // write-side swizzled col

  // ---- load whole att tile to regs (coalesced 256B runs) ----
  float4 va[7], vb[7];
#pragma unroll
  for (int ch = 0; ch < 7; ++ch) {
    int lg = ch * 32 + 2 * lp;
    va[ch] = float4{0.f, 0.f, 0.f, 0.f};
    vb[ch] = float4{0.f, 0.f, 0.f, 0.f};
    if (lg < Ll)
      va[ch] = *reinterpret_cast<const float4*>(&attb[(size_t)lg * 1024 + hq]);
    if (lg + 1 < Ll)
      vb[ch] = *reinterpret_cast<const float4*>(&attb[(size_t)(lg + 1) * 1024 + hq]);
  }
  // ---- issue panel half 0; stage epilogue params ----
#pragma unroll
  for (int j = 0; j < 4; ++j) {
    int c = (j << 2) + wn;
    async16(Pc + c * 1024 + lane * 16, &lds[CHB(0) + c * 1024]);
  }
  {
    float* phcL = reinterpret_cast<float*>(&lds[CH_PHC]);
    float* wbL = reinterpret_cast<float*>(&lds[CH_WB]);
    phcL[tid] = p_h[(size_t)b * 512 + tid] + b_ch[tid];
    phcL[tid + 256] = p_h[(size_t)b * 512 + tid + 256] + b_ch[tid + 256];
    wbL[tid] = w_beta[tid];
    wbL[tid + 256] = w_beta[tid + 256];
  }
  // ---- pack + write tile (bf16 l-pairs, quad-swizzled) ----
#pragma unroll
  for (int ch = 0; ch < 7; ++ch) {
    uint32 pk[4] = {packbf2(va[ch].x, vb[ch].x), packbf2(va[ch].y, vb[ch].y),
                    packbf2(va[ch].z, vb[ch].z), packbf2(va[ch].w, vb[ch].w)};
#pragma unroll
    for (int c = 0; c < 4; ++c)
      *reinterpret_cast<uint32*>(
          &lds[CH_TOFF + (hq + c) * CH_TSTR + ch * 64 + 4 * usw]) = pk[c];
  }

  f32x4 acc[4][4];
#pragma unroll
  for (int m = 0; m < 4; ++m)
#pragma unroll
    for (int n = 0; n < 4; ++n) acc[m][n] = f32x4{0.f, 0.f, 0.f, 0.f};
  float sn[4] = {0.f, 0.f, 0.f, 0.f};
  const float* phcLc = reinterpret_cast<const float*>(&lds[CH_PHC]);
  const float* wbLc = reinterpret_cast<const float*>(&lds[CH_WB]);
  __syncthreads();                          // tile + panel0 + params ready

  for (int s = 0; s < 14; ++s) {
    const int p = s & 1;
    if (s < 13) {                           // issue next half-panel
      int s1 = s + 1;
      const char* src = Pc + (size_t)(s1 % 7) * 32768 + (size_t)(s1 / 7) * 16384;
#pragma unroll
      for (int j = 0; j < 4; ++j) {
        int c = (j << 2) + wn;
        async16(src + c * 1024 + lane * 16, &lds[CHB(p ^ 1) + c * 1024]);
      }
    }
    const int t = (s >= 7) ? s - 7 : s;
    bf16x8 av[4], bv[4];
#pragma unroll
    for (int m = 0; m < 4; ++m)
      av[m] = *reinterpret_cast<const bf16x8*>(
          &lds[CHB(p) + (wn * 64 + m * 16 + l15) * 64 + slotP]);
#pragma unroll
    for (int n = 0; n < 4; ++n)
      bv[n] = *reinterpret_cast<const bf16x8*>(
          &lds[CH_TOFF + (n * 16 + l15) * CH_TSTR + t * 64 + slotT]);
#pragma unroll
    for (int n = 0; n < 4; ++n)
#pragma unroll
      for (int m = 0; m < 4; ++m)
        acc[m][n] = __builtin_amdgcn_mfma_f32_16x16x32_bf16(av[m], bv[n], acc[m][n], 0, 0, 0);
    __syncthreads();                        // next panel ready; CHB(p) free
    if (s == 6) {                           // epilogue half 0, reset acc
#pragma unroll
      for (int m = 0; m < 4; ++m) {
        int abase = wn * 64 + m * 16 + l4 * 4;
        float4 p4 = *reinterpret_cast<const float4*>(&phcLc[abase]);
        float4 w4 = *reinterpret_cast<const float4*>(&wbLc[abase]);
#pragma unroll
        for (int n = 0; n < 4; ++n) {
          sn[n] += fast_tanh(acc[m][n][0] + p4.x) * w4.x;
          sn[n] += fast_tanh(acc[m][n][1] + p4.y) * w4.y;
          sn[n] += fast_tanh(acc[m][n][2] + p4.z) * w4.z;
          sn[n] += fast_tanh(acc[m][n][3] + p4.w) * w4.w;
          acc[m][n] = f32x4{0.f, 0.f, 0.f, 0.f};
        }
      }
    }
  }
  // epilogue half 1
#pragma unroll
  for (int m = 0; m < 4; ++m) {
    int abase = 256 + wn * 64 + m * 16 + l4 * 4;
    float4 p4 = *reinterpret_cast<const float4*>(&phcLc[abase]);
    float4 w4 = *reinterpret_cast<const float4*>(&wbLc[abase]);
#pragma unroll
    for (int n = 0; n < 4; ++n) {
      sn[n] += fast_tanh(acc[m][n][0] + p4.x) * w4.x;
      sn[n] += fast_tanh(acc[m][n][1] + p4.y) * w4.y;
      sn[n] += fast_tanh(acc[m][n][2] + p4.z) * w4.z;
      sn[n] += fast_tanh(acc[m][n][3] + p4.w) * w4.w;
    }
  }
#pragma unroll
  for (int n = 0; n < 4; ++n) {
    sn[n] += __shfl_xor(sn[n], 16);
    sn[n] += __shfl_xor(sn[n], 32);
  }
  __syncthreads();
  float* red = reinterpret_cast<float*>(lds);
  if (l4 == 0) {
#pragma unroll
    for (int n = 0; n < 4; ++n) red[wn * 64 + n * 16 + l15] = sn[n];
  }
  __syncthreads();
  if (tid < 64)
    logits_c[(size_t)b * 1024 + h0 + tid] =
        red[tid] + red[64 + tid] + red[128 + tid] + red[192 + tid];
}

// ------------------------------- softmaxes ---------------------------------
__global__ void k_softmax_s(const float* __restrict__ logits, float* __restrict__ wout) {
  int b = blockIdx.x, t = threadIdx.x;
  __shared__ float sm[8];
  float x = (t < Ll) ? logits[(size_t)b * Ll + t] : -1e30f;
  float m = x;
#pragma unroll
  for (int o = 32; o; o >>= 1) m = fmaxf(m, __shfl_xor(m, o));
  if ((t & 63) == 0) sm[t >> 6] = m;
  __syncthreads();
  m = fmaxf(fmaxf(sm[0], sm[1]), fmaxf(sm[2], sm[3]));
  float e = (t < Ll) ? __expf(x - m) : 0.f;
  float s = e;
#pragma unroll
  for (int o = 32; o; o >>= 1) s += __shfl_xor(s, o);
  if ((t & 63) == 0) sm[4 + (t >> 6)] = s;
  __syncthreads();
  s = sm[4] + sm[5] + sm[6] + sm[7];
  if (t < Ll) wout[(size_t)b * Ll + t] = e / s;
}

__global__ void k_softmax_c(const float* __restrict__ logits, float* __restrict__ wout) {
  int b = blockIdx.x, t = threadIdx.x;
  __shared__ float sm[8];
  float4 x = *reinterpret_cast<const float4*>(&logits[(size_t)b * 1024 + (t << 2)]);
  float m = fmaxf(fmaxf(x.x, x.y), fmaxf(x.z, x.w));
#pragma unroll
  for (int o = 32; o; o >>= 1) m = fmaxf(m, __shfl_xor(m, o));
  if ((t & 63) == 0) sm[t >> 6] = m;
  __syncthreads();
  m = fmaxf(fmaxf(sm[0], sm[1]), fmaxf(sm[2], sm[3]));
  float e0 = __expf(x.x - m), e1 = __expf(x.y - m);
  float e2 = __expf(x.z - m), e3 = __expf(x.w - m);
  float s = e0 + e1 + e2 + e3;
#pragma unroll
  for (int o = 32; o; o >>= 1) s += __shfl_xor(s, o);
  if ((t & 63) == 0) sm[4 + (t >> 6)] = s;
  __syncthreads();
  float r = 1.f / (sm[4] + sm[5] + sm[6] + sm[7]);
  float4 o4 = {e0 * r, e1 * r, e2 * r, e3 * r};
  *reinterpret_cast<float4*>(&wout[(size_t)b * 1024 + (t << 2)]) = o4;
}

// --------------- fused weighted sums: one pass over att --------------------
__launch_bounds__(256)
__global__ void k_weighted(const float* __restrict__ att, const float* __restrict__ wsp,
                           const float* __restrict__ wch, float* __restrict__ out_s,
                           float* __restrict__ out_c) {
  int b = blockIdx.x, t = threadIdx.x;
  int lane = t & 63, wave = t >> 6;
  __shared__ float wsl[Ll];
  __shared__ float chan[4][Ll];
  if (t < Ll) wsl[t] = wsp[(size_t)b * Ll + t];
  float4 wc = *reinterpret_cast<const float4*>(&wch[(size_t)b * 1024 + (t << 2)]);
  float4 accs = {0.f, 0.f, 0.f, 0.f};
  __syncthreads();
  const float* attb = att + (size_t)b * Ll * 1024;
  for (int l = 0; l < Ll; ++l) {
    float4 v = *reinterpret_cast<const float4*>(&attb[(size_t)l * 1024 + (t << 2)]);
    float w = wsl[l];
    accs.x += w * v.x; accs.y += w * v.y; accs.z += w * v.z; accs.w += w * v.w;
    float pc = wc.x * v.x + wc.y * v.y + wc.z * v.z + wc.w * v.w;
#pragma unroll
    for (int o = 32; o; o >>= 1) pc += __shfl_xor(pc, o);
    if (lane == 0) chan[wave][l] = pc;
  }
  *reinterpret_cast<float4*>(&out_s[(size_t)b * 1024 + (t << 2)]) = accs;
  __syncthreads();
  if (t < Ll)
    out_c[(size_t)b * Ll + t] = chan[0][t] + chan[1][t] + chan[2][t] + chan[3][t];
}

// ------------------------------- launcher ----------------------------------
extern "C" void kernel_launch(void* const* d_in, const int* in_sizes, int n_in,
                              void* d_out, int out_size, void* d_ws, size_t ws_size,
                              hipStream_t stream) {
  (void)in_sizes; (void)n_in; (void)out_size; (void)ws_size;
  const float* att     = (const float*)d_in[0];
  const float* h       = (const float*)d_in[1];
  const float* W_att   = (const float*)d_in[2];
  const float* b_att   = (const float*)d_in[3];
  const float* W_h     = (const float*)d_in[4];
  const float* b_h     = (const float*)d_in[5];
  const float* w_alpha = (const float*)d_in[6];
  const float* W_ch    = (const float*)d_in[8];
  const float* b_ch    = (const float*)d_in[9];
  const float* w_beta  = (const float*)d_in[10];
  // d_in[7] b_alpha, d_in[11] b_beta: softmax-shift-invariant, unused

  float* out_ws    = (float*)d_out;                       // [B,H]
  float* out_wc    = out_ws + (size_t)Bb * Hh;            // [B,L]
  float* out_wspat = out_wc + (size_t)Bb * Ll;            // [B,L]

  char* ws = (char*)d_ws;
  float* p_h      = (float*)(ws);                          // 2 MB
  float* logits_s = (float*)(ws + 2097152);                // 802816 B
  float* logits_c = (float*)(ws + 2899968);                // 4 MB
  float* w_chan   = (float*)(ws + 7094272);                // 4 MB
  bf16*  WtP      = (bf16*)(ws + 11288576);                // 1 MB (32 panels)
  bf16*  WctP     = (bf16*)(ws + 12337152);                // 224 KB (7 panels)

  k_build_wt<<<256, 256, 0, stream>>>(W_att, WtP);
  k_build_wct<<<56, 256, 0, stream>>>(W_ch, WctP);
  k_ph<<<dim3(2, 128), 256, 0, stream>>>(h, W_h, b_h, p_h);
  k_spatial<<<BL / 64, 256, 0, stream>>>(att, WtP, b_att, p_h, w_alpha, logits_s);
  k_channel<<<dim3(16, 1024), 256, 0, stream>>>(att, WctP, b_ch, p_h, w_beta, logits_c);
  k_softmax_s<<<1024, 256, 0, stream>>>(logits_s, out_wspat);
  k_softmax_c<<<1024, 256, 0, stream>>>(logits_c, w_chan);
  k_weighted<<<1024, 256, 0, stream>>>(att, out_wspat, w_chan, out_ws, out_wc);
}

// Round 10
// 1195.856 us; speedup vs baseline: 1.2511x; 1.0671x over previous
//
#include <hip/hip_runtime.h>
#include <cstdint>
#include <cstddef>

// ---------------------------------------------------------------------------
// DualAttention: B=1024, L=196, H=1024, A=512
// R10 = R9 + THE fix: k_channel prologue's second half-panel is half(1) =
// panel 1 a-half 0 at Pc+32768, NOT Pc+16384 (= panel 0 a-half 1 = half(7)).
// R7-R9's identical absmax 0.126 was this deterministic wrong-address load —
// not a race (lesson: identical error across binaries => audit data mapping).
// Counted-vmcnt raw-barrier K-loops retained (R9 structure).
// ---------------------------------------------------------------------------

#define DEVI __device__ __forceinline__

typedef __bf16 bf16;
typedef bf16 bf16x4 __attribute__((ext_vector_type(4)));
typedef bf16 bf16x8 __attribute__((ext_vector_type(8)));
typedef float f32x4 __attribute__((ext_vector_type(4)));
typedef unsigned int uint32;

static constexpr int Bb = 1024;
static constexpr int Ll = 196;
static constexpr int Hh = 1024;
static constexpr int BL = Bb * Ll;        // 200704

#define VM_WAIT(N) asm volatile("s_waitcnt vmcnt(" #N ")" ::: "memory")
#define LGKM0     asm volatile("s_waitcnt lgkmcnt(0)" ::: "memory")
#define SBAR()    __builtin_amdgcn_s_barrier()
#define SCHED0()  __builtin_amdgcn_sched_barrier(0)

DEVI void async16(const void* g, void* l) {
  __builtin_amdgcn_global_load_lds(
      (const __attribute__((address_space(1))) void*)g,
      (__attribute__((address_space(3))) void*)l, 16, 0, 0);
}

DEVI float fast_tanh(float x) {
  float e = __expf(2.f * x);
  return 1.f - 2.f * __builtin_amdgcn_rcpf(e + 1.f);
}

DEVI uint32 packbf2(float a, float b) {
  union { bf16 h; unsigned short u; } x, y;
  x.h = (bf16)a; y.h = (bf16)b;
  return (uint32)x.u | ((uint32)y.u << 16);
}

// --------------------- weight panel builders (run once) --------------------
// Panels: [k0/32][a=0..511][64B]; 16B slot s holds k-octet (s ^ g(a)),
// g(a) = (a>>1)&3  (XOR baked at build; GEMM reads slot l4^g).
__global__ void k_build_wt(const float* __restrict__ W, bf16* __restrict__ P) {
  int idx = blockIdx.x * 256 + threadIdx.x;      // 65536
  int a = idx & 511;
  int ko = (idx >> 9) << 3;
  bf16x8 v;
#pragma unroll
  for (int j = 0; j < 8; ++j) v[j] = (bf16)W[(size_t)(ko + j) * 512 + a];
  int panel = ko >> 5;
  int slot = ((ko >> 3) & 3) ^ ((a >> 1) & 3);
  *reinterpret_cast<bf16x8*>((char*)P + (size_t)panel * 32768 + a * 64 + slot * 16) = v;
}

__global__ void k_build_wct(const float* __restrict__ W, bf16* __restrict__ P) {
  int idx = blockIdx.x * 256 + threadIdx.x;      // 14336
  int a = idx & 511;
  int lo = (idx >> 9) << 3;
  bf16x8 v;
#pragma unroll
  for (int j = 0; j < 8; ++j)
    v[j] = (lo + j < Ll) ? (bf16)W[(size_t)(lo + j) * 512 + a] : (bf16)0.f;
  int panel = lo >> 5;
  int slot = ((lo >> 3) & 3) ^ ((a >> 1) & 3);
  *reinterpret_cast<bf16x8*>((char*)P + (size_t)panel * 32768 + a * 64 + slot * 16) = v;
}

// ------------------------------- p_h = h@W_h -------------------------------
__global__ void k_ph(const float* __restrict__ h, const float* __restrict__ W_h,
                     const float* __restrict__ b_h, float* __restrict__ p_h) {
  int a = blockIdx.x * 256 + threadIdx.x;
  int b0 = blockIdx.y * 8;
  float acc[8] = {0.f, 0.f, 0.f, 0.f, 0.f, 0.f, 0.f, 0.f};
  for (int k = 0; k < 1024; ++k) {
    float w = W_h[(size_t)k * 512 + a];
#pragma unroll
    for (int i = 0; i < 8; ++i) acc[i] += h[(size_t)(b0 + i) * 1024 + k] * w;
  }
#pragma unroll
  for (int i = 0; i < 8; ++i) p_h[(size_t)(b0 + i) * 512 + a] = acc[i] + b_h[a];
}

// ---------------- spatial branch: fused GEMM + tanh-dot reduce -------------
// grid = BL/64 = 3136, 256 thr; tile 64 x 512, K=1024, 32 steps.
// LDS 70656: B dbuf 2x32KB at 0, A single 5120 at 65536.
#define SPB(p) ((p) * 32768)
#define SP_AOFF 65536
#define SP_ASTR 80
__launch_bounds__(256)
__global__ void k_spatial(const float* __restrict__ att, const bf16* __restrict__ WtP,
                          const float* __restrict__ b_att, const float* __restrict__ p_h,
                          const float* __restrict__ w_alpha, float* __restrict__ logits_s) {
  __shared__ alignas(1024) char lds[70656];
  const int tid = threadIdx.x;
  const int lane = tid & 63;
  const int wn = tid >> 6;
  const int l15 = lane & 15, l4 = lane >> 4;
  const size_t row0 = (size_t)blockIdx.x * 64;
  const int slotB = ((l4 ^ ((l15 >> 1) & 3)) << 4);
  const int ar = tid >> 2;                  // A rows 0..63
  const int aks = (tid & 3) << 3;           // k offset 0,8,16,24
  const char* WtPc = (const char*)WtP;
  const float* apbase = att + (row0 + ar) * 1024 + aks;
  const int awoff = SP_AOFF + ar * SP_ASTR + (aks << 1);

  f32x4 acc[4][8];
#pragma unroll
  for (int m = 0; m < 4; ++m)
#pragma unroll
    for (int n = 0; n < 8; ++n) acc[m][n] = f32x4{0.f, 0.f, 0.f, 0.f};

  // prologue: A(0),A(1) -> regs; issue B(0) | B(1); Abuf <- A(0); A(2) -> regs
  float4 c0x = *reinterpret_cast<const float4*>(apbase);
  float4 c0y = *reinterpret_cast<const float4*>(apbase + 4);
  float4 c1x = *reinterpret_cast<const float4*>(apbase + 32);
  float4 c1y = *reinterpret_cast<const float4*>(apbase + 36);
#pragma unroll
  for (int j = 0; j < 8; ++j) {
    int c = (j << 2) + wn;
    async16(WtPc + c * 1024 + lane * 16, &lds[SPB(0) + c * 1024]);
  }
  SCHED0();                                // pin: B(0) glls strictly before B(1)
#pragma unroll
  for (int j = 0; j < 8; ++j) {
    int c = (j << 2) + wn;
    async16(WtPc + 32768 + c * 1024 + lane * 16, &lds[SPB(1) + c * 1024]);
  }
  SCHED0();                                // pin: B(1) glls before anything below
  {
    bf16x4 w0 = {(bf16)c0x.x, (bf16)c0x.y, (bf16)c0x.z, (bf16)c0x.w};
    bf16x4 w1 = {(bf16)c0y.x, (bf16)c0y.y, (bf16)c0y.z, (bf16)c0y.w};
    *reinterpret_cast<bf16x4*>(&lds[awoff]) = w0;
    *reinterpret_cast<bf16x4*>(&lds[awoff + 8]) = w1;
  }
  c0x = *reinterpret_cast<const float4*>(apbase + 64);
  c0y = *reinterpret_cast<const float4*>(apbase + 68);
  VM_WAIT(2);                              // <=2 outstanding (A(2)) => B(0)+B(1) done
  LGKM0;
  SCHED0();
  SBAR();                                  // Abuf(A0) + Bbuf0 ready
  SCHED0();

  for (int t = 0; t < 32; ++t) {
    const int p = t & 1;
    // ---- consume step t ----
    bf16x8 af[4];
#pragma unroll
    for (int m = 0; m < 4; ++m)
      af[m] = *reinterpret_cast<const bf16x8*>(
          &lds[SP_AOFF + (m * 16 + l15) * SP_ASTR + (l4 << 4)]);
#pragma unroll
    for (int n = 0; n < 8; ++n) {
      bf16x8 bv = *reinterpret_cast<const bf16x8*>(
          &lds[SPB(p) + (wn * 128 + n * 16 + l15) * 64 + slotB]);
#pragma unroll
      for (int m = 0; m < 4; ++m)
        acc[m][n] = __builtin_amdgcn_mfma_f32_16x16x32_bf16(af[m], bv, acc[m][n], 0, 0, 0);
    }
    LGKM0;                                 // rule #18: ds_reads COMPLETE before BAR-A
    SCHED0();
    SBAR();                                // BAR-A: all waves done reading Abuf/Bbuf(p)
    SCHED0();
    if (t < 31) {
      // write A(t+1) into the (single) Abuf; reload the freed reg pair
      if ((t & 1) == 0) {
        bf16x4 w0 = {(bf16)c1x.x, (bf16)c1x.y, (bf16)c1x.z, (bf16)c1x.w};
        bf16x4 w1 = {(bf16)c1y.x, (bf16)c1y.y, (bf16)c1y.z, (bf16)c1y.w};
        *reinterpret_cast<bf16x4*>(&lds[awoff]) = w0;
        *reinterpret_cast<bf16x4*>(&lds[awoff + 8]) = w1;
        if (t <= 28) {
          c1x = *reinterpret_cast<const float4*>(apbase + (t + 3) * 32);
          c1y = *reinterpret_cast<const float4*>(apbase + (t + 3) * 32 + 4);
        }
      } else {
        bf16x4 w0 = {(bf16)c0x.x, (bf16)c0x.y, (bf16)c0x.z, (bf16)c0x.w};
        bf16x4 w1 = {(bf16)c0y.x, (bf16)c0y.y, (bf16)c0y.z, (bf16)c0y.w};
        *reinterpret_cast<bf16x4*>(&lds[awoff]) = w0;
        *reinterpret_cast<bf16x4*>(&lds[awoff + 8]) = w1;
        if (t <= 28) {
          c0x = *reinterpret_cast<const float4*>(apbase + (t + 3) * 32);
          c0y = *reinterpret_cast<const float4*>(apbase + (t + 3) * 32 + 4);
        }
      }
      if (t <= 29) {                       // issue B(t+2) into just-freed buf
        const char* bsrc = WtPc + (size_t)(t + 2) * 32768;
#pragma unroll
        for (int j = 0; j < 8; ++j) {
          int c = (j << 2) + wn;
          async16(bsrc + c * 1024 + lane * 16, &lds[SPB(p) + c * 1024]);
        }
      }
      LGKM0;                               // Abuf write visible
      if (t <= 28) { VM_WAIT(10); }        // <=10 newer (2 A + 8 B-glls) => B(t+1) done
      else if (t == 29) { VM_WAIT(8); }
      else { VM_WAIT(0); }                 // t == 30: only B(31) outstanding
      SCHED0();
      SBAR();                              // BAR-B: B(t+1)+A(t+1) ready
      SCHED0();
    }
  }

  // epilogue
  float wa[8], ba[8], ph0[8], ph1[8];
  unsigned b0i = (unsigned)row0 / 196u;
  unsigned b1i = (unsigned)(row0 + 63) / 196u;
  unsigned bnd = (b0i + 1) * 196u;
#pragma unroll
  for (int n = 0; n < 8; ++n) {
    int a = wn * 128 + n * 16 + l15;
    wa[n] = w_alpha[a];
    ba[n] = b_att[a];
    ph0[n] = p_h[(size_t)b0i * 512 + a];
    ph1[n] = p_h[(size_t)b1i * 512 + a];
  }
  float* red = reinterpret_cast<float*>(lds);
#pragma unroll
  for (int m = 0; m < 4; ++m) {
#pragma unroll
    for (int j = 0; j < 4; ++j) {
      int rloc = m * 16 + l4 * 4 + j;
      unsigned R = (unsigned)row0 + rloc;
      bool hib = R >= bnd;
      float s = 0.f;
#pragma unroll
      for (int n = 0; n < 8; ++n)
        s += fast_tanh(acc[m][n][j] + ba[n] + (hib ? ph1[n] : ph0[n])) * wa[n];
      s += __shfl_xor(s, 1);
      s += __shfl_xor(s, 2);
      s += __shfl_xor(s, 4);
      s += __shfl_xor(s, 8);
      if (l15 == 0) red[wn * 64 + rloc] = s;
    }
  }
  __syncthreads();
  if (tid < 64)
    logits_s[row0 + tid] = red[tid] + red[64 + tid] + red[128 + tid] + red[192 + tid];
}

// ---------------- channel branch: fused GEMM + tanh-dot reduce -------------
// grid = (16 h-tiles, 1024 b), 256 thr. D[a,h] = sum_l Wct[a,l]*att[b,l,h].
// att-tile staged ONCE (64h x 224l bf16, stride 464, quad swizzle); panel
// a-halves (16KB) dbuf via glls; counted vmcnt(4) loop, 2 raw barriers/step.
// Half-panel s (s=0..13) lives at Pc + (s%7)*32768 + (s/7)*16384.
#define CHB(p)  ((p) * 16384)
#define CH_TOFF 32768
#define CH_TSTR 464
#define CH_PHC  62464
#define CH_WB   64512
#define CH_LDSZ 66560
__launch_bounds__(256)
__global__ void k_channel(const float* __restrict__ att, const bf16* __restrict__ WctP,
                          const float* __restrict__ b_ch, const float* __restrict__ p_h,
                          const float* __restrict__ w_beta, float* __restrict__ logits_c) {
  __shared__ alignas(1024) char lds[CH_LDSZ];
  const int tid = threadIdx.x;
  const int lane = tid & 63;
  const int wn = tid >> 6;
  const int l15 = lane & 15, l4 = lane >> 4;
  const int b = blockIdx.y;
  const int h0 = blockIdx.x * 64;
  const float* attb = att + (size_t)b * Ll * 1024 + h0;
  const char* Pc = (const char*)WctP;
  const int slotP = (l4 ^ ((l15 >> 1) & 3)) << 4;     // panel read (baked XOR)
  const int slotT = (l4 ^ ((l15 >> 2) & 3)) << 4;     // tile read (row-XOR)
  const int lp = tid >> 4;                            // l-pair 0..15
  const int hq = (tid & 15) << 2;                     // h 0,4,...,60
  const int usw = lp ^ (((tid & 15) & 3) << 2);       // write-side swizzled col

  // ---- params first (oldest in VMEM queue) ----
  float pr0 = p_h[(size_t)b * 512 + tid];
  float pr1 = p_h[(size_t)b * 512 + tid + 256];
  float bc0 = b_ch[tid];
  float bc1 = b_ch[tid + 256];
  float wb0 = w_beta[tid];
  float wb1 = w_beta[tid + 256];
  // ---- whole att tile -> regs (coalesced 256B runs) ----
  float4 va[7], vb[7];
#pragma unroll
  for (int ch = 0; ch < 7; ++ch) {
    int lg = ch * 32 + 2 * lp;
    va[ch] = float4{0.f, 0.f, 0.f, 0.f};
    vb[ch] = float4{0.f, 0.f, 0.f, 0.f};
    if (lg < Ll)
      va[ch] = *reinterpret_cast<const float4*>(&attb[(size_t)lg * 1024 + hq]);
    if (lg + 1 < Ll)
      vb[ch] = *reinterpret_cast<const float4*>(&attb[(size_t)(lg + 1) * 1024 + hq]);
  }
  SCHED0();                                // pin: all reg loads before half0 glls
  // ---- issue half(0) | SCHED0 | half(1) ----
#pragma unroll
  for (int j = 0; j < 4; ++j) {
    int c = (j << 2) + wn;
    async16(Pc + c * 1024 + lane * 16, &lds[CHB(0) + c * 1024]);
  }
  SCHED0();                                // pin: half0 glls strictly before half1
#pragma unroll
  for (int j = 0; j < 4; ++j) {
    int c = (j << 2) + wn;
    // half(1) = panel 1, a-half 0  -> Pc + 1*32768  (R7-R9 bug: was Pc+16384)
    async16(Pc + 32768 + c * 1024 + lane * 16, &lds[CHB(1) + c * 1024]);
  }
  SCHED0();                                // pin: half1 glls before anything below
  // ---- pack + write tile (consumes tile regs; auto counted vmcnt) ----
#pragma unroll
  for (int ch = 0; ch < 7; ++ch) {
    uint32 pk[4] = {packbf2(va[ch].x, vb[ch].x), packbf2(va[ch].y, vb[ch].y),
                    packbf2(va[ch].z, vb[ch].z), packbf2(va[ch].w, vb[ch].w)};
#pragma unroll
    for (int c = 0; c < 4; ++c)
      *reinterpret_cast<uint32*>(
          &lds[CH_TOFF + (hq + c) * CH_TSTR + ch * 64 + 4 * usw]) = pk[c];
  }
  // ---- params to LDS ----
  {
    float* phcL = reinterpret_cast<float*>(&lds[CH_PHC]);
    float* wbL = reinterpret_cast<float*>(&lds[CH_WB]);
    phcL[tid] = pr0 + bc0;
    phcL[tid + 256] = pr1 + bc1;
    wbL[tid] = wb0;
    wbL[tid + 256] = wb1;
  }

  f32x4 acc[4][4];
#pragma unroll
  for (int m = 0; m < 4; ++m)
#pragma unroll
    for (int n = 0; n < 4; ++n) acc[m][n] = f32x4{0.f, 0.f, 0.f, 0.f};
  float sn[4] = {0.f, 0.f, 0.f, 0.f};
  const float* phcLc = reinterpret_cast<const float*>(&lds[CH_PHC]);
  const float* wbLc = reinterpret_cast<const float*>(&lds[CH_WB]);

  VM_WAIT(4);                              // half0 landed (only half1's 4 remain)
  LGKM0;
  SCHED0();
  SBAR();                                  // tile + half0 + params ready
  SCHED0();

  for (int s = 0; s < 14; ++s) {
    const int p = s & 1;
    const int tk = (s >= 7) ? s - 7 : s;
    bf16x8 av[4], bv[4];
#pragma unroll
    for (int m = 0; m < 4; ++m)
      av[m] = *reinterpret_cast<const bf16x8*>(
          &lds[CHB(p) + (wn * 64 + m * 16 + l15) * 64 + slotP]);
#pragma unroll
    for (int n = 0; n < 4; ++n)
      bv[n] = *reinterpret_cast<const bf16x8*>(
          &lds[CH_TOFF + (n * 16 + l15) * CH_TSTR + tk * 64 + slotT]);
#pragma unroll
    for (int n = 0; n < 4; ++n)
#pragma unroll
      for (int m = 0; m < 4; ++m)
        acc[m][n] = __builtin_amdgcn_mfma_f32_16x16x32_bf16(av[m], bv[n], acc[m][n], 0, 0, 0);
    if (s == 6) {                          // epilogue half 0, reset acc
#pragma unroll
      for (int m = 0; m < 4; ++m) {
        int abase = wn * 64 + m * 16 + l4 * 4;
        float4 p4 = *reinterpret_cast<const float4*>(&phcLc[abase]);
        float4 w4 = *reinterpret_cast<const float4*>(&wbLc[abase]);
#pragma unroll
        for (int n = 0; n < 4; ++n) {
          sn[n] += fast_tanh(acc[m][n][0] + p4.x) * w4.x;
          sn[n] += fast_tanh(acc[m][n][1] + p4.y) * w4.y;
          sn[n] += fast_tanh(acc[m][n][2] + p4.z) * w4.z;
          sn[n] += fast_tanh(acc[m][n][3] + p4.w) * w4.w;
          acc[m][n] = f32x4{0.f, 0.f, 0.f, 0.f};
        }
      }
    }
    LGKM0;                                 // rule #18: ds_reads COMPLETE before BAR-A
    SCHED0();
    SBAR();                                // BAR-A: all waves done reading CHB(p)
    SCHED0();
    if (s < 13) {
      if (s <= 11) {                       // issue half(s+2) into freed buf
        int s2 = s + 2;
        const char* src = Pc + (size_t)(s2 % 7) * 32768 + (size_t)(s2 / 7) * 16384;
#pragma unroll
        for (int j = 0; j < 4; ++j) {
          int c = (j << 2) + wn;
          async16(src + c * 1024 + lane * 16, &lds[CHB(p) + c * 1024]);
        }
        VM_WAIT(4);                        // half(s+1) landed
      } else {
        VM_WAIT(0);                        // s == 12: drain half(13)
      }
      SCHED0();
      SBAR();                              // BAR-B
      SCHED0();
    }
  }

  // epilogue half 1
#pragma unroll
  for (int m = 0; m < 4; ++m) {
    int abase = 256 + wn * 64 + m * 16 + l4 * 4;
    float4 p4 = *reinterpret_cast<const float4*>(&phcLc[abase]);
    float4 w4 = *reinterpret_cast<const float4*>(&wbLc[abase]);
#pragma unroll
    for (int n = 0; n < 4; ++n) {
      sn[n] += fast_tanh(acc[m][n][0] + p4.x) * w4.x;
      sn[n] += fast_tanh(acc[m][n][1] + p4.y) * w4.y;
      sn[n] += fast_tanh(acc[m][n][2] + p4.z) * w4.z;
      sn[n] += fast_tanh(acc[m][n][3] + p4.w) * w4.w;
    }
  }
#pragma unroll
  for (int n = 0; n < 4; ++n) {
    sn[n] += __shfl_xor(sn[n], 16);
    sn[n] += __shfl_xor(sn[n], 32);
  }
  __syncthreads();
  float* red = reinterpret_cast<float*>(lds);
  if (l4 == 0) {
#pragma unroll
    for (int n = 0; n < 4; ++n) red[wn * 64 + n * 16 + l15] = sn[n];
  }
  __syncthreads();
  if (tid < 64)
    logits_c[(size_t)b * 1024 + h0 + tid] =
        red[tid] + red[64 + tid] + red[128 + tid] + red[192 + tid];
}

// ------------------------------- softmaxes ---------------------------------
__global__ void k_softmax_s(const float* __restrict__ logits, float* __restrict__ wout) {
  int b = blockIdx.x, t = threadIdx.x;
  __shared__ float sm[8];
  float x = (t < Ll) ? logits[(size_t)b * Ll + t] : -1e30f;
  float m = x;
#pragma unroll
  for (int o = 32; o; o >>= 1) m = fmaxf(m, __shfl_xor(m, o));
  if ((t & 63) == 0) sm[t >> 6] = m;
  __syncthreads();
  m = fmaxf(fmaxf(sm[0], sm[1]), fmaxf(sm[2], sm[3]));
  float e = (t < Ll) ? __expf(x - m) : 0.f;
  float s = e;
#pragma unroll
  for (int o = 32; o; o >>= 1) s += __shfl_xor(s, o);
  if ((t & 63) == 0) sm[4 + (t >> 6)] = s;
  __syncthreads();
  s = sm[4] + sm[5] + sm[6] + sm[7];
  if (t < Ll) wout[(size_t)b * Ll + t] = e / s;
}

__global__ void k_softmax_c(const float* __restrict__ logits, float* __restrict__ wout) {
  int b = blockIdx.x, t = threadIdx.x;
  __shared__ float sm[8];
  float4 x = *reinterpret_cast<const float4*>(&logits[(size_t)b * 1024 + (t << 2)]);
  float m = fmaxf(fmaxf(x.x, x.y), fmaxf(x.z, x.w));
#pragma unroll
  for (int o = 32; o; o >>= 1) m = fmaxf(m, __shfl_xor(m, o));
  if ((t & 63) == 0) sm[t >> 6] = m;
  __syncthreads();
  m = fmaxf(fmaxf(sm[0], sm[1]), fmaxf(sm[2], sm[3]));
  float e0 = __expf(x.x - m), e1 = __expf(x.y - m);
  float e2 = __expf(x.z - m), e3 = __expf(x.w - m);
  float s = e0 + e1 + e2 + e3;
#pragma unroll
  for (int o = 32; o; o >>= 1) s += __shfl_xor(s, o);
  if ((t & 63) == 0) sm[4 + (t >> 6)] = s;
  __syncthreads();
  float r = 1.f / (sm[4] + sm[5] + sm[6] + sm[7]);
  float4 o4 = {e0 * r, e1 * r, e2 * r, e3 * r};
  *reinterpret_cast<float4*>(&wout[(size_t)b * 1024 + (t << 2)]) = o4;
}

// --------------- fused weighted sums: one pass over att --------------------
__launch_bounds__(256)
__global__ void k_weighted(const float* __restrict__ att, const float* __restrict__ wsp,
                           const float* __restrict__ wch, float* __restrict__ out_s,
                           float* __restrict__ out_c) {
  int b = blockIdx.x, t = threadIdx.x;
  int lane = t & 63, wave = t >> 6;
  __shared__ float wsl[Ll];
  __shared__ float chan[4][Ll];
  if (t < Ll) wsl[t] = wsp[(size_t)b * Ll + t];
  float4 wc = *reinterpret_cast<const float4*>(&wch[(size_t)b * 1024 + (t << 2)]);
  float4 accs = {0.f, 0.f, 0.f, 0.f};
  __syncthreads();
  const float* attb = att + (size_t)b * Ll * 1024;
  for (int l = 0; l < Ll; ++l) {
    float4 v = *reinterpret_cast<const float4*>(&attb[(size_t)l * 1024 + (t << 2)]);
    float w = wsl[l];
    accs.x += w * v.x; accs.y += w * v.y; accs.z += w * v.z; accs.w += w * v.w;
    float pc = wc.x * v.x + wc.y * v.y + wc.z * v.z + wc.w * v.w;
#pragma unroll
    for (int o = 32; o; o >>= 1) pc += __shfl_xor(pc, o);
    if (lane == 0) chan[wave][l] = pc;
  }
  *reinterpret_cast<float4*>(&out_s[(size_t)b * 1024 + (t << 2)]) = accs;
  __syncthreads();
  if (t < Ll)
    out_c[(size_t)b * Ll + t] = chan[0][t] + chan[1][t] + chan[2][t] + chan[3][t];
}

// ------------------------------- launcher ----------------------------------
extern "C" void kernel_launch(void* const* d_in, const int* in_sizes, int n_in,
                              void* d_out, int out_size, void* d_ws, size_t ws_size,
                              hipStream_t stream) {
  (void)in_sizes; (void)n_in; (void)out_size; (void)ws_size;
  const float* att     = (const float*)d_in[0];
  const float* h       = (const float*)d_in[1];
  const float* W_att   = (const float*)d_in[2];
  const float* b_att   = (const float*)d_in[3];
  const float* W_h     = (const float*)d_in[4];
  const float* b_h     = (const float*)d_in[5];
  const float* w_alpha = (const float*)d_in[6];
  const float* W_ch    = (const float*)d_in[8];
  const float* b_ch    = (const float*)d_in[9];
  const float* w_beta  = (const float*)d_in[10];
  // d_in[7] b_alpha, d_in[11] b_beta: softmax-shift-invariant, unused

  float* out_ws    = (float*)d_out;                       // [B,H]
  float* out_wc    = out_ws + (size_t)Bb * Hh;            // [B,L]
  float* out_wspat = out_wc + (size_t)Bb * Ll;            // [B,L]

  char* ws = (char*)d_ws;
  float* p_h      = (float*)(ws);                          // 2 MB
  float* logits_s = (float*)(ws + 2097152);                // 802816 B
  float* logits_c = (float*)(ws + 2899968);                // 4 MB
  float* w_chan   = (float*)(ws + 7094272);                // 4 MB
  bf16*  WtP      = (bf16*)(ws + 11288576);                // 1 MB (32 panels)
  bf16*  WctP     = (bf16*)(ws + 12337152);                // 224 KB (7 panels)

  k_build_wt<<<256, 256, 0, stream>>>(W_att, WtP);
  k_build_wct<<<56, 256, 0, stream>>>(W_ch, WctP);
  k_ph<<<dim3(2, 128), 256, 0, stream>>>(h, W_h, b_h, p_h);
  k_spatial<<<BL / 64, 256, 0, stream>>>(att, WtP, b_att, p_h, w_alpha, logits_s);
  k_channel<<<dim3(16, 1024), 256, 0, stream>>>(att, WctP, b_ch, p_h, w_beta, logits_c);
  k_softmax_s<<<1024, 256, 0, stream>>>(logits_s, out_wspat);
  k_softmax_c<<<1024, 256, 0, stream>>>(logits_c, w_chan);
  k_weighted<<<1024, 256, 0, stream>>>(att, out_wspat, w_chan, out_ws, out_wc);
}

// Round 11
// 1115.742 us; speedup vs baseline: 1.3409x; 1.0718x over previous
//
#include <hip/hip_runtime.h>
#include <cstdint>
#include <cstddef>

// ---------------------------------------------------------------------------
// DualAttention: B=1024, L=196, H=1024, A=512
// R11 = R10 with 512-thread GEMM blocks (8 waves): same grid, same per-block
// work, same LDS + counted-vmcnt skeleton, but 2x waves/SIMD (2 blocks/CU x
// 8 waves = 16 waves/CU if VGPR<=128). acc/wave halves (spatial 4x4=64 reg,
// channel 2x4=32 reg) so VALU+latency per wave halves and overlaps better.
// vmcnt counts re-derived for halved per-thread issue (spatial steady 5,
// channel steady 2).
// ---------------------------------------------------------------------------

#define DEVI __device__ __forceinline__

typedef __bf16 bf16;
typedef bf16 bf16x4 __attribute__((ext_vector_type(4)));
typedef bf16 bf16x8 __attribute__((ext_vector_type(8)));
typedef float f32x4 __attribute__((ext_vector_type(4)));
typedef unsigned int uint32;

static constexpr int Bb = 1024;
static constexpr int Ll = 196;
static constexpr int Hh = 1024;
static constexpr int BL = Bb * Ll;        // 200704

#define VM_WAIT(N) asm volatile("s_waitcnt vmcnt(" #N ")" ::: "memory")
#define LGKM0     asm volatile("s_waitcnt lgkmcnt(0)" ::: "memory")
#define SBAR()    __builtin_amdgcn_s_barrier()
#define SCHED0()  __builtin_amdgcn_sched_barrier(0)

DEVI void async16(const void* g, void* l) {
  __builtin_amdgcn_global_load_lds(
      (const __attribute__((address_space(1))) void*)g,
      (__attribute__((address_space(3))) void*)l, 16, 0, 0);
}

DEVI float fast_tanh(float x) {
  float e = __expf(2.f * x);
  return 1.f - 2.f * __builtin_amdgcn_rcpf(e + 1.f);
}

DEVI uint32 packbf2(float a, float b) {
  union { bf16 h; unsigned short u; } x, y;
  x.h = (bf16)a; y.h = (bf16)b;
  return (uint32)x.u | ((uint32)y.u << 16);
}

// --------------------- weight panel builders (run once) --------------------
// Panels: [k0/32][a=0..511][64B]; 16B slot s holds k-octet (s ^ g(a)),
// g(a) = (a>>1)&3  (XOR baked at build; GEMM reads slot l4^g).
__global__ void k_build_wt(const float* __restrict__ W, bf16* __restrict__ P) {
  int idx = blockIdx.x * 256 + threadIdx.x;      // 65536
  int a = idx & 511;
  int ko = (idx >> 9) << 3;
  bf16x8 v;
#pragma unroll
  for (int j = 0; j < 8; ++j) v[j] = (bf16)W[(size_t)(ko + j) * 512 + a];
  int panel = ko >> 5;
  int slot = ((ko >> 3) & 3) ^ ((a >> 1) & 3);
  *reinterpret_cast<bf16x8*>((char*)P + (size_t)panel * 32768 + a * 64 + slot * 16) = v;
}

__global__ void k_build_wct(const float* __restrict__ W, bf16* __restrict__ P) {
  int idx = blockIdx.x * 256 + threadIdx.x;      // 14336
  int a = idx & 511;
  int lo = (idx >> 9) << 3;
  bf16x8 v;
#pragma unroll
  for (int j = 0; j < 8; ++j)
    v[j] = (lo + j < Ll) ? (bf16)W[(size_t)(lo + j) * 512 + a] : (bf16)0.f;
  int panel = lo >> 5;
  int slot = ((lo >> 3) & 3) ^ ((a >> 1) & 3);
  *reinterpret_cast<bf16x8*>((char*)P + (size_t)panel * 32768 + a * 64 + slot * 16) = v;
}

// ------------------------------- p_h = h@W_h -------------------------------
__global__ void k_ph(const float* __restrict__ h, const float* __restrict__ W_h,
                     const float* __restrict__ b_h, float* __restrict__ p_h) {
  int a = blockIdx.x * 256 + threadIdx.x;
  int b0 = blockIdx.y * 8;
  float acc[8] = {0.f, 0.f, 0.f, 0.f, 0.f, 0.f, 0.f, 0.f};
  for (int k = 0; k < 1024; ++k) {
    float w = W_h[(size_t)k * 512 + a];
#pragma unroll
    for (int i = 0; i < 8; ++i) acc[i] += h[(size_t)(b0 + i) * 1024 + k] * w;
  }
#pragma unroll
  for (int i = 0; i < 8; ++i) p_h[(size_t)(b0 + i) * 512 + a] = acc[i] + b_h[a];
}

// ---------------- spatial branch: fused GEMM + tanh-dot reduce -------------
// grid = BL/64 = 3136, 512 thr (8 waves; wave wn owns cols wn*64..+63).
// LDS 70656: B dbuf 2x32KB at 0, A single 5120 at 65536.
#define SPB(p) ((p) * 32768)
#define SP_AOFF 65536
#define SP_ASTR 80
__launch_bounds__(512)
__global__ void k_spatial(const float* __restrict__ att, const bf16* __restrict__ WtP,
                          const float* __restrict__ b_att, const float* __restrict__ p_h,
                          const float* __restrict__ w_alpha, float* __restrict__ logits_s) {
  __shared__ alignas(1024) char lds[70656];
  const int tid = threadIdx.x;
  const int lane = tid & 63;
  const int wn = tid >> 6;                  // 0..7
  const int l15 = lane & 15, l4 = lane >> 4;
  const size_t row0 = (size_t)blockIdx.x * 64;
  const int slotB = ((l4 ^ ((l15 >> 1) & 3)) << 4);
  const int ar = tid >> 3;                  // A rows 0..63
  const int aks = (tid & 7) << 2;           // k offset 0,4,...,28
  const char* WtPc = (const char*)WtP;
  const float* apbase = att + (row0 + ar) * 1024 + aks;
  const int awoff = SP_AOFF + ar * SP_ASTR + (aks << 1);

  f32x4 acc[4][4];
#pragma unroll
  for (int m = 0; m < 4; ++m)
#pragma unroll
    for (int n = 0; n < 4; ++n) acc[m][n] = f32x4{0.f, 0.f, 0.f, 0.f};

  // prologue: A(0),A(1) -> regs; issue B(0) | B(1); Abuf <- A(0); A(2) -> regs
  float4 c0x = *reinterpret_cast<const float4*>(apbase);
  float4 c1x = *reinterpret_cast<const float4*>(apbase + 32);
#pragma unroll
  for (int j = 0; j < 4; ++j) {
    int c = (j << 3) + wn;
    async16(WtPc + c * 1024 + lane * 16, &lds[SPB(0) + c * 1024]);
  }
  SCHED0();                                // pin: B(0) glls strictly before B(1)
#pragma unroll
  for (int j = 0; j < 4; ++j) {
    int c = (j << 3) + wn;
    async16(WtPc + 32768 + c * 1024 + lane * 16, &lds[SPB(1) + c * 1024]);
  }
  SCHED0();                                // pin: B(1) glls before anything below
  {
    bf16x4 w0 = {(bf16)c0x.x, (bf16)c0x.y, (bf16)c0x.z, (bf16)c0x.w};
    *reinterpret_cast<bf16x4*>(&lds[awoff]) = w0;
  }
  c0x = *reinterpret_cast<const float4*>(apbase + 64);
  VM_WAIT(1);                              // <=1 outstanding (A(2)) => B(0)+B(1) done
  LGKM0;
  SCHED0();
  SBAR();                                  // Abuf(A0) + Bbuf0 ready
  SCHED0();

  for (int t = 0; t < 32; ++t) {
    const int p = t & 1;
    // ---- consume step t ----
    bf16x8 af[4];
#pragma unroll
    for (int m = 0; m < 4; ++m)
      af[m] = *reinterpret_cast<const bf16x8*>(
          &lds[SP_AOFF + (m * 16 + l15) * SP_ASTR + (l4 << 4)]);
#pragma unroll
    for (int n = 0; n < 4; ++n) {
      bf16x8 bv = *reinterpret_cast<const bf16x8*>(
          &lds[SPB(p) + (wn * 64 + n * 16 + l15) * 64 + slotB]);
#pragma unroll
      for (int m = 0; m < 4; ++m)
        acc[m][n] = __builtin_amdgcn_mfma_f32_16x16x32_bf16(af[m], bv, acc[m][n], 0, 0, 0);
    }
    LGKM0;                                 // rule #18: ds_reads COMPLETE before BAR-A
    SCHED0();
    SBAR();                                // BAR-A: all waves done reading Abuf/Bbuf(p)
    SCHED0();
    if (t < 31) {
      // write A(t+1) into the (single) Abuf; reload the freed reg
      if ((t & 1) == 0) {
        bf16x4 w0 = {(bf16)c1x.x, (bf16)c1x.y, (bf16)c1x.z, (bf16)c1x.w};
        *reinterpret_cast<bf16x4*>(&lds[awoff]) = w0;
        if (t <= 28)
          c1x = *reinterpret_cast<const float4*>(apbase + (t + 3) * 32);
      } else {
        bf16x4 w0 = {(bf16)c0x.x, (bf16)c0x.y, (bf16)c0x.z, (bf16)c0x.w};
        *reinterpret_cast<bf16x4*>(&lds[awoff]) = w0;
        if (t <= 28)
          c0x = *reinterpret_cast<const float4*>(apbase + (t + 3) * 32);
      }
      if (t <= 29) {                       // issue B(t+2) into just-freed buf
        const char* bsrc = WtPc + (size_t)(t + 2) * 32768;
#pragma unroll
        for (int j = 0; j < 4; ++j) {
          int c = (j << 3) + wn;
          async16(bsrc + c * 1024 + lane * 16, &lds[SPB(p) + c * 1024]);
        }
      }
      LGKM0;                               // Abuf write visible
      if (t <= 28) { VM_WAIT(5); }         // <=5 newer (1 A + 4 B-glls) => B(t+1) done
      else if (t == 29) { VM_WAIT(4); }
      else { VM_WAIT(0); }                 // t == 30: only B(31) outstanding
      SCHED0();
      SBAR();                              // BAR-B: B(t+1)+A(t+1) ready
      SCHED0();
    }
  }

  // epilogue: wave wn covers cols wn*64..+63 of all 64 rows
  float wa[4], ba[4], ph0[4], ph1[4];
  unsigned b0i = (unsigned)row0 / 196u;
  unsigned b1i = (unsigned)(row0 + 63) / 196u;
  unsigned bnd = (b0i + 1) * 196u;
#pragma unroll
  for (int n = 0; n < 4; ++n) {
    int a = wn * 64 + n * 16 + l15;
    wa[n] = w_alpha[a];
    ba[n] = b_att[a];
    ph0[n] = p_h[(size_t)b0i * 512 + a];
    ph1[n] = p_h[(size_t)b1i * 512 + a];
  }
  float* red = reinterpret_cast<float*>(lds);   // 8x64 floats
#pragma unroll
  for (int m = 0; m < 4; ++m) {
#pragma unroll
    for (int j = 0; j < 4; ++j) {
      int rloc = m * 16 + l4 * 4 + j;
      unsigned R = (unsigned)row0 + rloc;
      bool hib = R >= bnd;
      float s = 0.f;
#pragma unroll
      for (int n = 0; n < 4; ++n)
        s += fast_tanh(acc[m][n][j] + ba[n] + (hib ? ph1[n] : ph0[n])) * wa[n];
      s += __shfl_xor(s, 1);
      s += __shfl_xor(s, 2);
      s += __shfl_xor(s, 4);
      s += __shfl_xor(s, 8);
      if (l15 == 0) red[wn * 64 + rloc] = s;
    }
  }
  __syncthreads();
  if (tid < 64) {
    float r = 0.f;
#pragma unroll
    for (int w = 0; w < 8; ++w) r += red[w * 64 + tid];
    logits_s[row0 + tid] = r;
  }
}

// ---------------- channel branch: fused GEMM + tanh-dot reduce -------------
// grid = (16 h-tiles, 1024 b), 512 thr (8 waves; wave wn owns a-rows wn*32
// within each half-panel). att-tile staged ONCE (waves 0-3); panel a-halves
// (16KB) dbuf via glls; counted vmcnt(2) loop, 2 raw barriers/step.
// Half-panel s (s=0..13) lives at Pc + (s%7)*32768 + (s/7)*16384.
#define CHB(p)  ((p) * 16384)
#define CH_TOFF 32768
#define CH_TSTR 464
#define CH_PHC  62464
#define CH_WB   64512
#define CH_LDSZ 66560
__launch_bounds__(512)
__global__ void k_channel(const float* __restrict__ att, const bf16* __restrict__ WctP,
                          const float* __restrict__ b_ch, const float* __restrict__ p_h,
                          const float* __restrict__ w_beta, float* __restrict__ logits_c) {
  __shared__ alignas(1024) char lds[CH_LDSZ];
  const int tid = threadIdx.x;
  const int lane = tid & 63;
  const int wn = tid >> 6;                  // 0..7
  const int l15 = lane & 15, l4 = lane >> 4;
  const int b = blockIdx.y;
  const int h0 = blockIdx.x * 64;
  const float* attb = att + (size_t)b * Ll * 1024 + h0;
  const char* Pc = (const char*)WctP;
  const int slotP = (l4 ^ ((l15 >> 1) & 3)) << 4;     // panel read (baked XOR)
  const int slotT = (l4 ^ ((l15 >> 2) & 3)) << 4;     // tile read (row-XOR)
  const int lp = (tid >> 4) & 15;                     // l-pair 0..15 (tid<256)
  const int hq = (tid & 15) << 2;                     // h 0,4,...,60
  const int usw = lp ^ ((tid & 3) << 2);              // write-side swizzled col

  // ---- params (1 each; oldest in VMEM queue) ----
  float pr = p_h[(size_t)b * 512 + tid];
  float bc = b_ch[tid];
  float wb = w_beta[tid];
  // ---- whole att tile -> regs, waves 0-3 only (coalesced 256B runs) ----
  float4 va[7], vb[7];
  if (tid < 256) {
#pragma unroll
    for (int ch = 0; ch < 7; ++ch) {
      int lg = ch * 32 + 2 * lp;
      va[ch] = float4{0.f, 0.f, 0.f, 0.f};
      vb[ch] = float4{0.f, 0.f, 0.f, 0.f};
      if (lg < Ll)
        va[ch] = *reinterpret_cast<const float4*>(&attb[(size_t)lg * 1024 + hq]);
      if (lg + 1 < Ll)
        vb[ch] = *reinterpret_cast<const float4*>(&attb[(size_t)(lg + 1) * 1024 + hq]);
    }
  }
  SCHED0();                                // pin: all reg loads before half0 glls
  // ---- issue half(0) | SCHED0 | half(1) ----
#pragma unroll
  for (int j = 0; j < 2; ++j) {
    int c = (j << 3) + wn;
    async16(Pc + c * 1024 + lane * 16, &lds[CHB(0) + c * 1024]);
  }
  SCHED0();                                // pin: half0 glls strictly before half1
#pragma unroll
  for (int j = 0; j < 2; ++j) {
    int c = (j << 3) + wn;
    async16(Pc + 32768 + c * 1024 + lane * 16, &lds[CHB(1) + c * 1024]);
  }
  SCHED0();                                // pin: half1 glls before anything below
  // ---- pack + write tile (waves 0-3; consumes tile regs; auto vmcnt) ----
  if (tid < 256) {
#pragma unroll
    for (int ch = 0; ch < 7; ++ch) {
      uint32 pk[4] = {packbf2(va[ch].x, vb[ch].x), packbf2(va[ch].y, vb[ch].y),
                      packbf2(va[ch].z, vb[ch].z), packbf2(va[ch].w, vb[ch].w)};
#pragma unroll
      for (int c = 0; c < 4; ++c)
        *reinterpret_cast<uint32*>(
            &lds[CH_TOFF + (hq + c) * CH_TSTR + ch * 64 + 4 * usw]) = pk[c];
    }
  }
  // ---- params to LDS ----
  {
    float* phcL = reinterpret_cast<float*>(&lds[CH_PHC]);
    float* wbL = reinterpret_cast<float*>(&lds[CH_WB]);
    phcL[tid] = pr + bc;
    wbL[tid] = wb;
  }

  f32x4 acc[2][4];
#pragma unroll
  for (int m = 0; m < 2; ++m)
#pragma unroll
    for (int n = 0; n < 4; ++n) acc[m][n] = f32x4{0.f, 0.f, 0.f, 0.f};
  float sn[4] = {0.f, 0.f, 0.f, 0.f};
  const float* phcLc = reinterpret_cast<const float*>(&lds[CH_PHC]);
  const float* wbLc = reinterpret_cast<const float*>(&lds[CH_WB]);

  VM_WAIT(2);                              // half0 landed (only half1's 2 remain)
  LGKM0;
  SCHED0();
  SBAR();                                  // tile + half0 + params ready
  SCHED0();

  for (int s = 0; s < 14; ++s) {
    const int p = s & 1;
    const int tk = (s >= 7) ? s - 7 : s;
    bf16x8 av[2], bv[4];
#pragma unroll
    for (int m = 0; m < 2; ++m)
      av[m] = *reinterpret_cast<const bf16x8*>(
          &lds[CHB(p) + (wn * 32 + m * 16 + l15) * 64 + slotP]);
#pragma unroll
    for (int n = 0; n < 4; ++n)
      bv[n] = *reinterpret_cast<const bf16x8*>(
          &lds[CH_TOFF + (n * 16 + l15) * CH_TSTR + tk * 64 + slotT]);
#pragma unroll
    for (int n = 0; n < 4; ++n)
#pragma unroll
      for (int m = 0; m < 2; ++m)
        acc[m][n] = __builtin_amdgcn_mfma_f32_16x16x32_bf16(av[m], bv[n], acc[m][n], 0, 0, 0);
    if (s == 6) {                          // epilogue half 0 (a in [0,256)), reset acc
#pragma unroll
      for (int m = 0; m < 2; ++m) {
        int abase = wn * 32 + m * 16 + l4 * 4;
        float4 p4 = *reinterpret_cast<const float4*>(&phcLc[abase]);
        float4 w4 = *reinterpret_cast<const float4*>(&wbLc[abase]);
#pragma unroll
        for (int n = 0; n < 4; ++n) {
          sn[n] += fast_tanh(acc[m][n][0] + p4.x) * w4.x;
          sn[n] += fast_tanh(acc[m][n][1] + p4.y) * w4.y;
          sn[n] += fast_tanh(acc[m][n][2] + p4.z) * w4.z;
          sn[n] += fast_tanh(acc[m][n][3] + p4.w) * w4.w;
          acc[m][n] = f32x4{0.f, 0.f, 0.f, 0.f};
        }
      }
    }
    LGKM0;                                 // rule #18: ds_reads COMPLETE before BAR-A
    SCHED0();
    SBAR();                                // BAR-A: all waves done reading CHB(p)
    SCHED0();
    if (s < 13) {
      if (s <= 11) {                       // issue half(s+2) into freed buf
        int s2 = s + 2;
        const char* src = Pc + (size_t)(s2 % 7) * 32768 + (size_t)(s2 / 7) * 16384;
#pragma unroll
        for (int j = 0; j < 2; ++j) {
          int c = (j << 3) + wn;
          async16(src + c * 1024 + lane * 16, &lds[CHB(p) + c * 1024]);
        }
        VM_WAIT(2);                        // half(s+1) landed
      } else {
        VM_WAIT(0);                        // s == 12: drain half(13)
      }
      SCHED0();
      SBAR();                              // BAR-B
      SCHED0();
    }
  }

  // epilogue half 1 (a in [256,512))
#pragma unroll
  for (int m = 0; m < 2; ++m) {
    int abase = 256 + wn * 32 + m * 16 + l4 * 4;
    float4 p4 = *reinterpret_cast<const float4*>(&phcLc[abase]);
    float4 w4 = *reinterpret_cast<const float4*>(&wbLc[abase]);
#pragma unroll
    for (int n = 0; n < 4; ++n) {
      sn[n] += fast_tanh(acc[m][n][0] + p4.x) * w4.x;
      sn[n] += fast_tanh(acc[m][n][1] + p4.y) * w4.y;
      sn[n] += fast_tanh(acc[m][n][2] + p4.z) * w4.z;
      sn[n] += fast_tanh(acc[m][n][3] + p4.w) * w4.w;
    }
  }
#pragma unroll
  for (int n = 0; n < 4; ++n) {
    sn[n] += __shfl_xor(sn[n], 16);
    sn[n] += __shfl_xor(sn[n], 32);
  }
  __syncthreads();
  float* red = reinterpret_cast<float*>(lds);   // 8x64 floats
  if (l4 == 0) {
#pragma unroll
    for (int n = 0; n < 4; ++n) red[wn * 64 + n * 16 + l15] = sn[n];
  }
  __syncthreads();
  if (tid < 64) {
    float r = 0.f;
#pragma unroll
    for (int w = 0; w < 8; ++w) r += red[w * 64 + tid];
    logits_c[(size_t)b * 1024 + h0 + tid] = r;
  }
}

// ------------------------------- softmaxes ---------------------------------
__global__ void k_softmax_s(const float* __restrict__ logits, float* __restrict__ wout) {
  int b = blockIdx.x, t = threadIdx.x;
  __shared__ float sm[8];
  float x = (t < Ll) ? logits[(size_t)b * Ll + t] : -1e30f;
  float m = x;
#pragma unroll
  for (int o = 32; o; o >>= 1) m = fmaxf(m, __shfl_xor(m, o));
  if ((t & 63) == 0) sm[t >> 6] = m;
  __syncthreads();
  m = fmaxf(fmaxf(sm[0], sm[1]), fmaxf(sm[2], sm[3]));
  float e = (t < Ll) ? __expf(x - m) : 0.f;
  float s = e;
#pragma unroll
  for (int o = 32; o; o >>= 1) s += __shfl_xor(s, o);
  if ((t & 63) == 0) sm[4 + (t >> 6)] = s;
  __syncthreads();
  s = sm[4] + sm[5] + sm[6] + sm[7];
  if (t < Ll) wout[(size_t)b * Ll + t] = e / s;
}

__global__ void k_softmax_c(const float* __restrict__ logits, float* __restrict__ wout) {
  int b = blockIdx.x, t = threadIdx.x;
  __shared__ float sm[8];
  float4 x = *reinterpret_cast<const float4*>(&logits[(size_t)b * 1024 + (t << 2)]);
  float m = fmaxf(fmaxf(x.x, x.y), fmaxf(x.z, x.w));
#pragma unroll
  for (int o = 32; o; o >>= 1) m = fmaxf(m, __shfl_xor(m, o));
  if ((t & 63) == 0) sm[t >> 6] = m;
  __syncthreads();
  m = fmaxf(fmaxf(sm[0], sm[1]), fmaxf(sm[2], sm[3]));
  float e0 = __expf(x.x - m), e1 = __expf(x.y - m);
  float e2 = __expf(x.z - m), e3 = __expf(x.w - m);
  float s = e0 + e1 + e2 + e3;
#pragma unroll
  for (int o = 32; o; o >>= 1) s += __shfl_xor(s, o);
  if ((t & 63) == 0) sm[4 + (t >> 6)] = s;
  __syncthreads();
  float r = 1.f / (sm[4] + sm[5] + sm[6] + sm[7]);
  float4 o4 = {e0 * r, e1 * r, e2 * r, e3 * r};
  *reinterpret_cast<float4*>(&wout[(size_t)b * 1024 + (t << 2)]) = o4;
}

// --------------- fused weighted sums: one pass over att --------------------
__launch_bounds__(256)
__global__ void k_weighted(const float* __restrict__ att, const float* __restrict__ wsp,
                           const float* __restrict__ wch, float* __restrict__ out_s,
                           float* __restrict__ out_c) {
  int b = blockIdx.x, t = threadIdx.x;
  int lane = t & 63, wave = t >> 6;
  __shared__ float wsl[Ll];
  __shared__ float chan[4][Ll];
  if (t < Ll) wsl[t] = wsp[(size_t)b * Ll + t];
  float4 wc = *reinterpret_cast<const float4*>(&wch[(size_t)b * 1024 + (t << 2)]);
  float4 accs = {0.f, 0.f, 0.f, 0.f};
  __syncthreads();
  const float* attb = att + (size_t)b * Ll * 1024;
  for (int l = 0; l < Ll; ++l) {
    float4 v = *reinterpret_cast<const float4*>(&attb[(size_t)l * 1024 + (t << 2)]);
    float w = wsl[l];
    accs.x += w * v.x; accs.y += w * v.y; accs.z += w * v.z; accs.w += w * v.w;
    float pc = wc.x * v.x + wc.y * v.y + wc.z * v.z + wc.w * v.w;
#pragma unroll
    for (int o = 32; o; o >>= 1) pc += __shfl_xor(pc, o);
    if (lane == 0) chan[wave][l] = pc;
  }
  *reinterpret_cast<float4*>(&out_s[(size_t)b * 1024 + (t << 2)]) = accs;
  __syncthreads();
  if (t < Ll)
    out_c[(size_t)b * Ll + t] = chan[0][t] + chan[1][t] + chan[2][t] + chan[3][t];
}

// ------------------------------- launcher ----------------------------------
extern "C" void kernel_launch(void* const* d_in, const int* in_sizes, int n_in,
                              void* d_out, int out_size, void* d_ws, size_t ws_size,
                              hipStream_t stream) {
  (void)in_sizes; (void)n_in; (void)out_size; (void)ws_size;
  const float* att     = (const float*)d_in[0];
  const float* h       = (const float*)d_in[1];
  const float* W_att   = (const float*)d_in[2];
  const float* b_att   = (const float*)d_in[3];
  const float* W_h     = (const float*)d_in[4];
  const float* b_h     = (const float*)d_in[5];
  const float* w_alpha = (const float*)d_in[6];
  const float* W_ch    = (const float*)d_in[8];
  const float* b_ch    = (const float*)d_in[9];
  const float* w_beta  = (const float*)d_in[10];
  // d_in[7] b_alpha, d_in[11] b_beta: softmax-shift-invariant, unused

  float* out_ws    = (float*)d_out;                       // [B,H]
  float* out_wc    = out_ws + (size_t)Bb * Hh;            // [B,L]
  float* out_wspat = out_wc + (size_t)Bb * Ll;            // [B,L]

  char* ws = (char*)d_ws;
  float* p_h      = (float*)(ws);                          // 2 MB
  float* logits_s = (float*)(ws + 2097152);                // 802816 B
  float* logits_c = (float*)(ws + 2899968);                // 4 MB
  float* w_chan   = (float*)(ws + 7094272);                // 4 MB
  bf16*  WtP      = (bf16*)(ws + 11288576);                // 1 MB (32 panels)
  bf16*  WctP     = (bf16*)(ws + 12337152);                // 224 KB (7 panels)

  k_build_wt<<<256, 256, 0, stream>>>(W_att, WtP);
  k_build_wct<<<56, 256, 0, stream>>>(W_ch, WctP);
  k_ph<<<dim3(2, 128), 256, 0, stream>>>(h, W_h, b_h, p_h);
  k_spatial<<<BL / 64, 512, 0, stream>>>(att, WtP, b_att, p_h, w_alpha, logits_s);
  k_channel<<<dim3(16, 1024), 512, 0, stream>>>(att, WctP, b_ch, p_h, w_beta, logits_c);
  k_softmax_s<<<1024, 256, 0, stream>>>(logits_s, out_wspat);
  k_softmax_c<<<1024, 256, 0, stream>>>(logits_c, w_chan);
  k_weighted<<<1024, 256, 0, stream>>>(att, out_wspat, w_chan, out_ws, out_wc);
}